// Round 2
// baseline (188.886 us; speedup 1.0000x reference)
//
#include <hip/hip_runtime.h>
#include <math.h>

#define BATCH 8192
typedef unsigned short u16;
typedef unsigned int u32;
typedef __attribute__((ext_vector_type(8))) short bf16x8;
typedef __attribute__((ext_vector_type(4))) float f32x4;
typedef __attribute__((ext_vector_type(4))) unsigned short u16x4;

__device__ __forceinline__ float sigm(float v) { return 1.0f / (1.0f + __expf(-v)); }
__device__ __forceinline__ u16 f2bf(float f) {
    union { float f; u32 u; } v; v.f = f;
    u32 r = v.u + 0x7FFFu + ((v.u >> 16) & 1u);   // RNE
    return (u16)(r >> 16);
}
__device__ __forceinline__ float bf2f(u16 h) {
    union { u32 u; float f; } v; v.u = ((u32)h) << 16; return v.f;
}
__device__ __forceinline__ void split_store4(float4 v, u16* hp, u16* lp) {
    u16 h0 = f2bf(v.x), h1 = f2bf(v.y), h2 = f2bf(v.z), h3 = f2bf(v.w);
    u16x4 hv = {h0, h1, h2, h3};
    u16x4 lv = {f2bf(v.x - bf2f(h0)), f2bf(v.y - bf2f(h1)),
                f2bf(v.z - bf2f(h2)), f2bf(v.w - bf2f(h3))};
    *(u16x4*)hp = hv; *(u16x4*)lp = lv;
}
// fragment-linear B: element [(nt*nch + ch)*64 + lane]*8 + e  ==  B[nt*16+(lane&15)][ch*32+(lane>>4)*8+e]
__device__ __forceinline__ bf16x8 bfrag(const u16* Bf, int nt, int ch, int nch, int lane) {
    return *(const bf16x8*)(Bf + (((size_t)nt * nch + ch) * 64 + lane) * 8);
}
#define MFMA(a, b, c) __builtin_amdgcn_mfma_f32_16x16x32_bf16(a, b, c, 0, 0, 0)

// ---------------- workspace layout (u16 elements); hi plane then lo plane ----------------
#define S_FBT 69632   // [17 nt][8 ch] frag-linear, n<272, k<256
#define S_B1  61440   // 3 taps x [8 nt][5 ch], n<128, k<160
#define S_B2A 16384   // [4 nt][8 ch]
#define S_B2B 24576   // [4 nt][12 ch]
#define S_B3  8192    // [4 nt][4 ch]
#define S_B4  8192    // [8 nt][2 ch]
#define S_BL  131072  // [32 nt][8 ch]  n = gate*128+j, k: 0..127 W / 128..255 U
#define P_FBT 0
#define P_B1  139264
#define P_B2A 262144
#define P_B2B 294912
#define P_B3  344064
#define P_B4  360448
#define P_BL  376832
#define N_PREP 319488

// ---------------- k_prep: build fragment-linear split-bf16 B planes ----------------
__global__ __launch_bounds__(256) void k_prep(const float* __restrict__ fb,
                                              const float* __restrict__ w1, const float* __restrict__ w2,
                                              const float* __restrict__ w3, const float* __restrict__ w4,
                                              const float* __restrict__ wi, const float* __restrict__ wf,
                                              const float* __restrict__ wg, const float* __restrict__ wo,
                                              const float* __restrict__ ui, const float* __restrict__ uf,
                                              const float* __restrict__ ug, const float* __restrict__ uo,
                                              u16* __restrict__ wsu) {
    const float* Ws[8] = {wi, wf, wg, wo, ui, uf, ug, uo};
    for (int i = blockIdx.x * 256 + threadIdx.x; i < N_PREP; i += gridDim.x * 256) {
        int r = i;
        float v; int P, S, idx;
        if (r < S_FBT) {                                    // FBT nch=8
            int f = r >> 9, lane = (r & 511) >> 3, e = r & 7;
            int n = (f >> 3) * 16 + (lane & 15), k = (f & 7) * 32 + (lane >> 4) * 8 + e;
            int c = n >> 1, part = n & 1;
            v = (n < 258) ? fb[(size_t)(c + part * 129) * 256 + k] : 0.f;
            P = P_FBT; S = S_FBT; idx = r;
        } else if ((r -= S_FBT) < S_B1) {                   // B1: 3 taps, nch=5
            int kk = r / 20480, r2 = r - kk * 20480;
            int f = r2 >> 9, lane = (r2 & 511) >> 3, e = r2 & 7;
            int n = (f / 5) * 16 + (lane & 15), k = (f % 5) * 32 + (lane >> 4) * 8 + e;
            v = (k < 129) ? w1[(size_t)n * 387 + k * 3 + kk] : 0.f;
            P = P_B1; S = S_B1; idx = r;
        } else if ((r -= S_B1) < S_B2A) {                   // B2A nch=8
            int f = r >> 9, lane = (r & 511) >> 3, e = r & 7;
            int n = (f >> 3) * 16 + (lane & 15), k = (f & 7) * 32 + (lane >> 4) * 8 + e;
            v = w2[(size_t)n * 384 + (k & 127) * 3 + (k >> 7) + 1];
            P = P_B2A; S = S_B2A; idx = r;
        } else if ((r -= S_B2A) < S_B2B) {                  // B2B nch=12
            int f = r >> 9, lane = (r & 511) >> 3, e = r & 7;
            int n = (f / 12) * 16 + (lane & 15), k = (f % 12) * 32 + (lane >> 4) * 8 + e;
            v = w2[(size_t)n * 384 + (k & 127) * 3 + (k >> 7)];
            P = P_B2B; S = S_B2B; idx = r;
        } else if ((r -= S_B2B) < S_B3) {                   // B3 nch=4
            int f = r >> 9, lane = (r & 511) >> 3, e = r & 7;
            int n = (f >> 2) * 16 + (lane & 15), k = (f & 3) * 32 + (lane >> 4) * 8 + e;
            v = w3[(size_t)n * 192 + (k & 63) * 3 + (k >> 6) + 1];
            P = P_B3; S = S_B3; idx = r;
        } else if ((r -= S_B3) < S_B4) {                    // B4 nch=2
            int f = r >> 9, lane = (r & 511) >> 3, e = r & 7;
            int n = (f >> 1) * 16 + (lane & 15), k = (f & 1) * 32 + (lane >> 4) * 8 + e;
            v = w4[(size_t)n * 192 + k * 3 + 1];
            P = P_B4; S = S_B4; idx = r;
        } else {                                            // BL nch=8
            r -= S_B4;
            int f = r >> 9, lane = (r & 511) >> 3, e = r & 7;
            int n = (f >> 3) * 16 + (lane & 15), k = (f & 7) * 32 + (lane >> 4) * 8 + e;
            int g = n >> 7, j = n & 127;
            v = Ws[g + ((k >= 128) ? 4 : 0)][(size_t)j * 128 + (k & 127)];
            P = P_BL; S = S_BL; idx = r;
        }
        u16 h = f2bf(v);
        wsu[P + idx] = h;
        wsu[P + S + idx] = f2bf(v - bf2f(h));
    }
}

// ---------------- k_all: STFT -> mag -> enc1 -> enc2 -> enc3 -> enc4 -> LSTM -> head ----------------
// block 512 (8 waves), 8 batches (32 stft rows, mt=2), grid 1024 (= 4 blocks/CU, 32 waves/CU).
// __launch_bounds__(512,8) forces <=64 unified regs so 4 blocks/CU is register-feasible.
// LDS union (u16), 16128 elems = 31.5 KB, time-multiplexed:
//   phase A: audio  aAh[0,5760) aAl[5760,11520)    stride 720 (conflict-free)
//   phase B: mag    mAh[0,8064) mAl[8064,16128)    rows bb*6+tp, stride 168
//   phase C: e1     eAh[0,4160) eAl[4160,8320)     rows=batch, stride 520
//            s2 [8320,10496) s3 [10496,11648) xh [11648,15872) pr [15872,16128)
// Post-enc1 stages have M=8 real rows in the 16-row fragment: A-row addrs masked (&7),
// stores / per-batch global accesses guarded with quad<2 (rows 8..15 are duplicates).
__global__ __launch_bounds__(512, 8) void k_all(const float* __restrict__ audio,
                                             const u16* __restrict__ wsu,
                                             const float* __restrict__ hin, const float* __restrict__ cin,
                                             const float* __restrict__ b1, const float* __restrict__ b2,
                                             const float* __restrict__ b3, const float* __restrict__ b4,
                                             const float* __restrict__ bxi, const float* __restrict__ bxf,
                                             const float* __restrict__ bxg, const float* __restrict__ bxo,
                                             const float* __restrict__ bhi, const float* __restrict__ bhf,
                                             const float* __restrict__ bhg, const float* __restrict__ bho,
                                             const float* __restrict__ cw, const float* __restrict__ cb,
                                             float* __restrict__ out) {
    __shared__ __align__(16) u16 uni[16128];
    u16* aAh = uni;
    u16* aAl = uni + 5760;
    u16* mAh = uni;
    u16* mAl = uni + 8064;
    u16* eAh = uni;
    u16* eAl = uni + 4160;
    u16* s2h = uni + 8320;
    u16* s2l = uni + 9408;
    u16* s3h = uni + 10496;
    u16* s3l = uni + 11072;
    u16* xhh = uni + 11648;
    u16* xhl = uni + 13760;
    float* pr = (float*)(uni + 15872);
    const int tid = threadIdx.x;
    const int b0 = blockIdx.x << 3;
    // ---- phase A: stage audio (split bf16, reflect pad) ----
    for (int i = tid; i < 8 * 160; i += 512) {
        int bb = i / 160, j4 = (i - bb * 160) * 4;
        const float* ap = audio + (size_t)(b0 + bb) * 576;
        float4 v;
        if (j4 < 576) v = *(const float4*)(ap + j4);
        else { v.x = ap[1150 - j4]; v.y = ap[1149 - j4]; v.z = ap[1148 - j4]; v.w = ap[1147 - j4]; }
        int phys = bb * 720 + j4 + (j4 >> 7) * 8;
        split_store4(v, aAh + phys, aAl + phys);
    }
    __syncthreads();
    const int lane = tid & 63, w = tid >> 6;
    const int m = lane & 15, quad = lane >> 4;
    // ---- GEMM1 (STFT): wave w owns nt = 2w..2w+1 (w==7 also nt=16), mt=2 ----
    const u16* fbT = wsu + P_FBT;
    const int tcnt = (w == 7) ? 3 : 2;
    f32x4 acc[2][3];
    #pragma unroll
    for (int mt = 0; mt < 2; ++mt)
        #pragma unroll
        for (int t = 0; t < 3; ++t) acc[mt][t] = (f32x4){0.f, 0.f, 0.f, 0.f};
    for (int ch = 0; ch < 8; ++ch) {
        bf16x8 ah[2], al[2];
        #pragma unroll
        for (int mt = 0; mt < 2; ++mt) {
            int Rm = mt * 16 + m;
            int phys = (Rm >> 2) * 720 + (Rm & 3) * 136 + ch * 32 + quad * 8 + ((ch >= 4) ? 8 : 0);
            ah[mt] = *(const bf16x8*)(aAh + phys);
            al[mt] = *(const bf16x8*)(aAl + phys);
        }
        #pragma unroll
        for (int tt = 0; tt < 3; ++tt) {
            if (tt < tcnt) {
                int t = w * 2 + tt;
                bf16x8 bh = bfrag(fbT, t, ch, 8, lane);
                bf16x8 bl_ = bfrag(fbT + S_FBT, t, ch, 8, lane);
                #pragma unroll
                for (int mt = 0; mt < 2; ++mt) {
                    acc[mt][tt] = MFMA(ah[mt], bh, acc[mt][tt]);
                    acc[mt][tt] = MFMA(ah[mt], bl_, acc[mt][tt]);
                    acc[mt][tt] = MFMA(al[mt], bh, acc[mt][tt]);
                }
            }
        }
    }
    __syncthreads();                                // audio dead
    for (int i = tid; i < 8064; i += 512) ((u32*)uni)[i] = 0u;   // zero union (mag pads)
    __syncthreads();
    // ---- magnitude epilogue -> mag LDS ----
    #pragma unroll
    for (int tt = 0; tt < 3; ++tt) {
        if (tt < tcnt) {
            int n = (w * 2 + tt) * 16 + m;
            #pragma unroll
            for (int mt = 0; mt < 2; ++mt)
                #pragma unroll
                for (int r = 0; r < 4; ++r) {
                    float vv = acc[mt][tt][r];
                    float s = vv * vv;
                    s += __shfl_xor(s, 1);
                    if (!(n & 1)) {
                        int R = mt * 16 + quad * 4 + r;
                        int bb = R >> 2, t = R & 3, c = n >> 1;
                        float sv = sqrtf(s);
                        u16 h = f2bf(sv);
                        int phys = (bb * 6 + t + 1) * 168 + c;
                        mAh[phys] = h;
                        mAl[phys] = f2bf(sv - bf2f(h));
                    }
                }
        }
    }
    __syncthreads();
    // ---- GEMM2 (enc1): wave w owns nt = w (N=128), mt=2, K = 3 taps x 5 ch ----
    const u16* B1h = wsu + P_B1;
    const u16* B1l = wsu + P_B1 + S_B1;
    f32x4 acc2[2];
    #pragma unroll
    for (int mt = 0; mt < 2; ++mt) acc2[mt] = (f32x4){0.f, 0.f, 0.f, 0.f};
    for (int kk = 0; kk < 3; ++kk) {
        for (int ch = 0; ch < 5; ++ch) {
            bf16x8 bh = bfrag(B1h + kk * 20480, w, ch, 5, lane);
            bf16x8 bl_ = bfrag(B1l + kk * 20480, w, ch, 5, lane);
            #pragma unroll
            for (int mt = 0; mt < 2; ++mt) {
                int Rm = mt * 16 + m;
                int phys = ((Rm >> 2) * 6 + (Rm & 3) + kk) * 168 + ch * 32 + quad * 8;
                bf16x8 ah = *(const bf16x8*)(mAh + phys);
                bf16x8 al = *(const bf16x8*)(mAl + phys);
                acc2[mt] = MFMA(ah, bh, acc2[mt]);
                acc2[mt] = MFMA(ah, bl_, acc2[mt]);
                acc2[mt] = MFMA(al, bh, acc2[mt]);
            }
        }
    }
    __syncthreads();                                // mag dead
    // ---- e1 -> LDS (split), h -> xh cols 128..255 ----
    {
        int n = w * 16 + m;
        float bv = b1[n];
        #pragma unroll
        for (int mt = 0; mt < 2; ++mt)
            #pragma unroll
            for (int r = 0; r < 4; ++r) {
                int R = mt * 16 + quad * 4 + r;
                float vv = fmaxf(acc2[mt][r] + bv, 0.f);
                u16 h = f2bf(vv);
                int phys = (R >> 2) * 520 + (R & 3) * 128 + n;
                eAh[phys] = h;
                eAl[phys] = f2bf(vv - bf2f(h));
            }
    }
    for (int i = tid; i < 8 * 32; i += 512) {
        int row = i >> 5, c4 = (i & 31) * 4;
        float4 v = *(const float4*)(hin + (size_t)(b0 + row) * 128 + c4);
        split_store4(v, xhh + row * 264 + 128 + c4, xhl + row * 264 + 128 + c4);
    }
    __syncthreads();
    // ---- enc2: waves 0-3 = enc2a (K=256), waves 4-7 = enc2b (K=384) ----
    {
        const int isB = w >> 2, nt = w & 3;
        const int awoff = isB ? 128 : 0;
        const int nch = isB ? 12 : 8;
        const u16* Bh = wsu + (isB ? P_B2B : P_B2A);
        const u16* Bl = Bh + (isB ? S_B2B : S_B2A);
        f32x4 a2 = (f32x4){0.f, 0.f, 0.f, 0.f};
        for (int ch = 0; ch < nch; ++ch) {
            int phys = (m & 7) * 520 + awoff + ch * 32 + quad * 8;
            bf16x8 ah = *(const bf16x8*)(eAh + phys);
            bf16x8 al = *(const bf16x8*)(eAl + phys);
            bf16x8 bh = bfrag(Bh, nt, ch, nch, lane);
            bf16x8 bl_ = bfrag(Bl, nt, ch, nch, lane);
            a2 = MFMA(ah, bh, a2);
            a2 = MFMA(ah, bl_, a2);
            a2 = MFMA(al, bh, a2);
        }
        const int oc = nt * 16 + m;
        const float bv = b2[oc];
        const int col = isB * 64 + oc;
        if (quad < 2) {
            #pragma unroll
            for (int r = 0; r < 4; ++r) {
                int row = quad * 4 + r;
                float vv = fmaxf(a2[r] + bv, 0.f);
                u16 h = f2bf(vv);
                s2h[row * 136 + col] = h;
                s2l[row * 136 + col] = f2bf(vv - bf2f(h));
            }
        }
    }
    __syncthreads();
    // ---- enc3: waves 0-3, K=128 (4 ch), N=64 ----
    if (w < 4) {
        const u16* Bh = wsu + P_B3;
        const u16* Bl = Bh + S_B3;
        f32x4 a3 = (f32x4){0.f, 0.f, 0.f, 0.f};
        for (int ch = 0; ch < 4; ++ch) {
            int phys = (m & 7) * 136 + ch * 32 + quad * 8;
            bf16x8 ah = *(const bf16x8*)(s2h + phys);
            bf16x8 al = *(const bf16x8*)(s2l + phys);
            bf16x8 bh = bfrag(Bh, w, ch, 4, lane);
            bf16x8 bl_ = bfrag(Bl, w, ch, 4, lane);
            a3 = MFMA(ah, bh, a3);
            a3 = MFMA(ah, bl_, a3);
            a3 = MFMA(al, bh, a3);
        }
        const int n = w * 16 + m;
        const float bv = b3[n];
        if (quad < 2) {
            #pragma unroll
            for (int r = 0; r < 4; ++r) {
                int row = quad * 4 + r;
                float vv = fmaxf(a3[r] + bv, 0.f);
                u16 h = f2bf(vv);
                s3h[row * 72 + n] = h;
                s3l[row * 72 + n] = f2bf(vv - bf2f(h));
            }
        }
    }
    __syncthreads();
    // ---- enc4: all 8 waves, K=64 (2 ch), N=128 -> x into xh cols 0..127 ----
    {
        const u16* Bh = wsu + P_B4;
        const u16* Bl = Bh + S_B4;
        f32x4 a4 = (f32x4){0.f, 0.f, 0.f, 0.f};
        for (int ch = 0; ch < 2; ++ch) {
            int phys = (m & 7) * 72 + ch * 32 + quad * 8;
            bf16x8 ah = *(const bf16x8*)(s3h + phys);
            bf16x8 al = *(const bf16x8*)(s3l + phys);
            bf16x8 bh = bfrag(Bh, w, ch, 2, lane);
            bf16x8 bl_ = bfrag(Bl, w, ch, 2, lane);
            a4 = MFMA(ah, bh, a4);
            a4 = MFMA(ah, bl_, a4);
            a4 = MFMA(al, bh, a4);
        }
        const int n = w * 16 + m;
        const float bv = b4[n];
        if (quad < 2) {
            #pragma unroll
            for (int r = 0; r < 4; ++r) {
                int row = quad * 4 + r;
                float vv = fmaxf(a4[r] + bv, 0.f);
                u16 h = f2bf(vv);
                xhh[row * 264 + n] = h;
                xhl[row * 264 + n] = f2bf(vv - bf2f(h));
            }
        }
    }
    __syncthreads();
    // ---- LSTM: wave w owns j-tile w x all 4 gates; K=256 (8 ch) ----
    {
        const u16* BLh = wsu + P_BL;
        const u16* BLl = BLh + S_BL;
        f32x4 ag[4];
        #pragma unroll
        for (int g = 0; g < 4; ++g) ag[g] = (f32x4){0.f, 0.f, 0.f, 0.f};
        #pragma unroll 2
        for (int ch = 0; ch < 8; ++ch) {
            int phys = (m & 7) * 264 + ch * 32 + quad * 8;
            bf16x8 ah = *(const bf16x8*)(xhh + phys);
            bf16x8 al = *(const bf16x8*)(xhl + phys);
            #pragma unroll
            for (int g = 0; g < 4; ++g) {
                int nt = g * 8 + w;
                bf16x8 bh = bfrag(BLh, nt, ch, 8, lane);
                bf16x8 bl_ = bfrag(BLl, nt, ch, 8, lane);
                ag[g] = MFMA(ah, bh, ag[g]);
                ag[g] = MFMA(ah, bl_, ag[g]);
                ag[g] = MFMA(al, bh, ag[g]);
            }
        }
        float partial[4];
        const int j = w * 16 + m;
        const float bi = bxi[j] + bhi[j];
        const float bff = bxf[j] + bhf[j];
        const float bgg = bxg[j] + bhg[j];
        const float boo = bxo[j] + bho[j];
        const float cwj = cw[j];
        #pragma unroll
        for (int r = 0; r < 4; ++r) {
            if (quad < 2) {
                const int b = b0 + quad * 4 + r;
                const float ig = sigm(ag[0][r] + bi);
                const float fg = sigm(ag[1][r] + bff);
                const float gg = tanhf(ag[2][r] + bgg);
                const float og = sigm(ag[3][r] + boo);
                const float ci = cin[(size_t)b * 128 + j];
                const float co = fg * ci + ig * gg;
                const float ho = og * tanhf(co);
                out[(size_t)BATCH + (size_t)b * 128 + j] = ho;
                out[(size_t)BATCH + (size_t)BATCH * 128 + (size_t)b * 128 + j] = co;
                partial[r] = fmaxf(ho, 0.f) * cwj;
            } else {
                partial[r] = 0.f;
            }
        }
        #pragma unroll
        for (int off = 1; off < 16; off <<= 1)
            #pragma unroll
            for (int r = 0; r < 4; ++r) partial[r] += __shfl_xor(partial[r], off);
        if (m == 0) {
            #pragma unroll
            for (int r = 0; r < 4; ++r) pr[w * 16 + quad * 4 + r] = partial[r];
        }
    }
    __syncthreads();
    if (tid < 8) {
        float s = cb[0];
        #pragma unroll
        for (int g = 0; g < 8; ++g) s += pr[g * 16 + tid];
        out[b0 + tid] = sigm(s);
    }
}

extern "C" void kernel_launch(void* const* d_in, const int* in_sizes, int n_in,
                              void* d_out, int out_size, void* d_ws, size_t ws_size,
                              hipStream_t stream) {
    const float* audio = (const float*)d_in[0];
    const float* hin   = (const float*)d_in[1];
    const float* cin   = (const float*)d_in[2];
    const float* fb    = (const float*)d_in[3];
    const float* w1    = (const float*)d_in[4];
    const float* b1    = (const float*)d_in[5];
    const float* w2    = (const float*)d_in[6];
    const float* b2    = (const float*)d_in[7];
    const float* w3    = (const float*)d_in[8];
    const float* b3    = (const float*)d_in[9];
    const float* w4    = (const float*)d_in[10];
    const float* b4    = (const float*)d_in[11];
    const float* wi    = (const float*)d_in[12];
    const float* wf    = (const float*)d_in[13];
    const float* wg    = (const float*)d_in[14];
    const float* wo    = (const float*)d_in[15];
    const float* ui    = (const float*)d_in[16];
    const float* uf    = (const float*)d_in[17];
    const float* ug    = (const float*)d_in[18];
    const float* uo    = (const float*)d_in[19];
    const float* bxi   = (const float*)d_in[20];
    const float* bxf   = (const float*)d_in[21];
    const float* bxg   = (const float*)d_in[22];
    const float* bxo   = (const float*)d_in[23];
    const float* bhi   = (const float*)d_in[24];
    const float* bhf   = (const float*)d_in[25];
    const float* bhg   = (const float*)d_in[26];
    const float* bho   = (const float*)d_in[27];
    const float* cw    = (const float*)d_in[28];
    const float* cb    = (const float*)d_in[29];
    float* out = (float*)d_out;

    u16* wsu = (u16*)d_ws;

    k_prep<<<640, 256, 0, stream>>>(fb, w1, w2, w3, w4, wi, wf, wg, wo, ui, uf, ug, uo, wsu);
    k_all<<<BATCH / 8, 512, 0, stream>>>(audio, wsu, hin, cin, b1, b2, b3, b4,
                                         bxi, bxf, bxg, bxo, bhi, bhf, bhg, bho,
                                         cw, cb, out);
}

// Round 4
// 186.832 us; speedup vs baseline: 1.0110x; 1.0110x over previous
//
#include <hip/hip_runtime.h>
#include <math.h>

#define BATCH 8192
typedef unsigned short u16;
typedef unsigned int u32;
typedef __attribute__((ext_vector_type(8))) short bf16x8;
typedef __attribute__((ext_vector_type(4))) float f32x4;
typedef __attribute__((ext_vector_type(4))) unsigned short u16x4;

__device__ __forceinline__ float sigm(float v) { return 1.0f / (1.0f + __expf(-v)); }
__device__ __forceinline__ u16 f2bf(float f) {
    union { float f; u32 u; } v; v.f = f;
    u32 r = v.u + 0x7FFFu + ((v.u >> 16) & 1u);   // RNE
    return (u16)(r >> 16);
}
__device__ __forceinline__ float bf2f(u16 h) {
    union { u32 u; float f; } v; v.u = ((u32)h) << 16; return v.f;
}
__device__ __forceinline__ void split_store4(float4 v, u16* hp, u16* lp) {
    u16 h0 = f2bf(v.x), h1 = f2bf(v.y), h2 = f2bf(v.z), h3 = f2bf(v.w);
    u16x4 hv = {h0, h1, h2, h3};
    u16x4 lv = {f2bf(v.x - bf2f(h0)), f2bf(v.y - bf2f(h1)),
                f2bf(v.z - bf2f(h2)), f2bf(v.w - bf2f(h3))};
    *(u16x4*)hp = hv; *(u16x4*)lp = lv;
}
// fragment-linear B: element [(nt*nch + ch)*64 + lane]*8 + e  ==  B[nt*16+(lane&15)][ch*32+(lane>>4)*8+e]
__device__ __forceinline__ bf16x8 bfrag(const u16* Bf, int nt, int ch, int nch, int lane) {
    return *(const bf16x8*)(Bf + (((size_t)nt * nch + ch) * 64 + lane) * 8);
}
#define MFMA(a, b, c) __builtin_amdgcn_mfma_f32_16x16x32_bf16(a, b, c, 0, 0, 0)

// ---------------- workspace layout (u16 elements); hi plane then lo plane ----------------
#define S_FBT 69632   // [17 nt][8 ch] frag-linear, n<272, k<256
#define S_B1  61440   // 3 taps x [8 nt][5 ch], n<128, k<160
#define S_B2A 16384   // [4 nt][8 ch]
#define S_B2B 24576   // [4 nt][12 ch]
#define S_B3  8192    // [4 nt][4 ch]
#define S_B4  8192    // [8 nt][2 ch]
#define S_BL  131072  // [32 nt][8 ch]  n = gate*128+j, k: 0..127 W / 128..255 U
#define P_FBT 0
#define P_B1  139264
#define P_B2A 262144
#define P_B2B 294912
#define P_B3  344064
#define P_B4  360448
#define P_BL  376832
#define N_PREP 319488

// ---------------- k_prep: build fragment-linear split-bf16 B planes ----------------
__global__ __launch_bounds__(256) void k_prep(const float* __restrict__ fb,
                                              const float* __restrict__ w1, const float* __restrict__ w2,
                                              const float* __restrict__ w3, const float* __restrict__ w4,
                                              const float* __restrict__ wi, const float* __restrict__ wf,
                                              const float* __restrict__ wg, const float* __restrict__ wo,
                                              const float* __restrict__ ui, const float* __restrict__ uf,
                                              const float* __restrict__ ug, const float* __restrict__ uo,
                                              u16* __restrict__ wsu) {
    const float* Ws[8] = {wi, wf, wg, wo, ui, uf, ug, uo};
    for (int i = blockIdx.x * 256 + threadIdx.x; i < N_PREP; i += gridDim.x * 256) {
        int r = i;
        float v; int P, S, idx;
        if (r < S_FBT) {                                    // FBT nch=8
            int f = r >> 9, lane = (r & 511) >> 3, e = r & 7;
            int n = (f >> 3) * 16 + (lane & 15), k = (f & 7) * 32 + (lane >> 4) * 8 + e;
            int c = n >> 1, part = n & 1;
            v = (n < 258) ? fb[(size_t)(c + part * 129) * 256 + k] : 0.f;
            P = P_FBT; S = S_FBT; idx = r;
        } else if ((r -= S_FBT) < S_B1) {                   // B1: 3 taps, nch=5
            int kk = r / 20480, r2 = r - kk * 20480;
            int f = r2 >> 9, lane = (r2 & 511) >> 3, e = r2 & 7;
            int n = (f / 5) * 16 + (lane & 15), k = (f % 5) * 32 + (lane >> 4) * 8 + e;
            v = (k < 129) ? w1[(size_t)n * 387 + k * 3 + kk] : 0.f;
            P = P_B1; S = S_B1; idx = r;
        } else if ((r -= S_B1) < S_B2A) {                   // B2A nch=8
            int f = r >> 9, lane = (r & 511) >> 3, e = r & 7;
            int n = (f >> 3) * 16 + (lane & 15), k = (f & 7) * 32 + (lane >> 4) * 8 + e;
            v = w2[(size_t)n * 384 + (k & 127) * 3 + (k >> 7) + 1];
            P = P_B2A; S = S_B2A; idx = r;
        } else if ((r -= S_B2A) < S_B2B) {                  // B2B nch=12
            int f = r >> 9, lane = (r & 511) >> 3, e = r & 7;
            int n = (f / 12) * 16 + (lane & 15), k = (f % 12) * 32 + (lane >> 4) * 8 + e;
            v = w2[(size_t)n * 384 + (k & 127) * 3 + (k >> 7)];
            P = P_B2B; S = S_B2B; idx = r;
        } else if ((r -= S_B2B) < S_B3) {                   // B3 nch=4
            int f = r >> 9, lane = (r & 511) >> 3, e = r & 7;
            int n = (f >> 2) * 16 + (lane & 15), k = (f & 3) * 32 + (lane >> 4) * 8 + e;
            v = w3[(size_t)n * 192 + (k & 63) * 3 + (k >> 6) + 1];
            P = P_B3; S = S_B3; idx = r;
        } else if ((r -= S_B3) < S_B4) {                    // B4 nch=2
            int f = r >> 9, lane = (r & 511) >> 3, e = r & 7;
            int n = (f >> 1) * 16 + (lane & 15), k = (f & 1) * 32 + (lane >> 4) * 8 + e;
            v = w4[(size_t)n * 192 + k * 3 + 1];
            P = P_B4; S = S_B4; idx = r;
        } else {                                            // BL nch=8
            r -= S_B4;
            int f = r >> 9, lane = (r & 511) >> 3, e = r & 7;
            int n = (f >> 3) * 16 + (lane & 15), k = (f & 7) * 32 + (lane >> 4) * 8 + e;
            int g = n >> 7, j = n & 127;
            v = Ws[g + ((k >= 128) ? 4 : 0)][(size_t)j * 128 + (k & 127)];
            P = P_BL; S = S_BL; idx = r;
        }
        u16 h = f2bf(v);
        wsu[P + idx] = h;
        wsu[P + S + idx] = f2bf(v - bf2f(h));
    }
}

// ---------------- k_all: STFT -> mag -> enc1 -> enc2 -> enc3 -> enc4 -> LSTM -> head ----------------
// block 512 (8 waves), 16 batches (64 stft rows), grid 512 (= 2 blocks/CU).
// LDS-pipe-bound (round-2 finding): waves split 2-way over M (mt-groups) x fewer N-groups
// so per-block LDS A-fragment reads HALVE (1824 -> 912 b128) at identical MFMA count.
// GEMM1/GEMM2: wave = (wh = w>>2 mt-group) x (g = w&3 nt-group).
// enc2/enc4/LSTM: waves 0-3 (2 nt each); enc3: waves 0-1.
// LDS union (u16), 63 KB, time-multiplexed (identical to round-0 map):
//   phase A: audio  aAh[0,11520) aAl[11520,23040)   stride 720 (conflict-free)
//   phase B: mag    mAh[0,16128) mAl[16128,32256)   rows bb*6+tp, stride 168
//   phase C: e1     eAh[0,8320)  eAl[8320,16640)    rows=batch, stride 520
//            s2 [16640,20992) s3 [20992,23296) xh [23296,31744) pr [31744,32256)
// NOTE: the zero-loop must cover the FULL mag union = 16128 u32 (round-3 bug: 8064 left
// the mAl plane holding stale LDS -> garbage in lo-plane conv pads -> absmax 2.3e-2).
__global__ __launch_bounds__(512, 4) void k_all(const float* __restrict__ audio,
                                             const u16* __restrict__ wsu,
                                             const float* __restrict__ hin, const float* __restrict__ cin,
                                             const float* __restrict__ b1, const float* __restrict__ b2,
                                             const float* __restrict__ b3, const float* __restrict__ b4,
                                             const float* __restrict__ bxi, const float* __restrict__ bxf,
                                             const float* __restrict__ bxg, const float* __restrict__ bxo,
                                             const float* __restrict__ bhi, const float* __restrict__ bhf,
                                             const float* __restrict__ bhg, const float* __restrict__ bho,
                                             const float* __restrict__ cw, const float* __restrict__ cb,
                                             float* __restrict__ out) {
    __shared__ __align__(16) u16 uni[32256];
    u16* aAh = uni;
    u16* aAl = uni + 11520;
    u16* mAh = uni;
    u16* mAl = uni + 16128;
    u16* eAh = uni;
    u16* eAl = uni + 8320;
    u16* s2h = uni + 16640;
    u16* s2l = uni + 18816;
    u16* s3h = uni + 20992;
    u16* s3l = uni + 22144;
    u16* xhh = uni + 23296;
    u16* xhl = uni + 27520;
    float* pr = (float*)(uni + 31744);
    const int tid = threadIdx.x;
    const int b0 = blockIdx.x << 4;
    // ---- phase A: stage audio (split bf16, reflect pad) ----
    for (int i = tid; i < 16 * 160; i += 512) {
        int bb = i / 160, j4 = (i - bb * 160) * 4;
        const float* ap = audio + (size_t)(b0 + bb) * 576;
        float4 v;
        if (j4 < 576) v = *(const float4*)(ap + j4);
        else { v.x = ap[1150 - j4]; v.y = ap[1149 - j4]; v.z = ap[1148 - j4]; v.w = ap[1147 - j4]; }
        int phys = bb * 720 + j4 + (j4 >> 7) * 8;
        split_store4(v, aAh + phys, aAl + phys);
    }
    __syncthreads();
    const int lane = tid & 63, w = tid >> 6;
    const int m = lane & 15, quad = lane >> 4;
    const int wh = w >> 2;          // mt-group: rows (wh*2+mt2)*16 + m
    const int g  = w & 3;           // nt-group
    // ---- GEMM1 (STFT): wave (wh,g): mts {2wh,2wh+1}, tiles {4g..4g+3} (+tile16 for g==3) ----
    const u16* fbT = wsu + P_FBT;
    const int tcnt = (g == 3) ? 5 : 4;
    f32x4 acc[2][5];
    #pragma unroll
    for (int mt2 = 0; mt2 < 2; ++mt2)
        #pragma unroll
        for (int t = 0; t < 5; ++t) acc[mt2][t] = (f32x4){0.f, 0.f, 0.f, 0.f};
    for (int ch = 0; ch < 8; ++ch) {
        bf16x8 ah[2], al[2];
        #pragma unroll
        for (int mt2 = 0; mt2 < 2; ++mt2) {
            int Rm = (wh * 2 + mt2) * 16 + m;
            int phys = (Rm >> 2) * 720 + (Rm & 3) * 136 + ch * 32 + quad * 8 + ((ch >= 4) ? 8 : 0);
            ah[mt2] = *(const bf16x8*)(aAh + phys);
            al[mt2] = *(const bf16x8*)(aAl + phys);
        }
        #pragma unroll
        for (int tt = 0; tt < 5; ++tt) {
            if (tt < tcnt) {
                int t = g * 4 + tt;
                bf16x8 bh = bfrag(fbT, t, ch, 8, lane);
                bf16x8 bl_ = bfrag(fbT + S_FBT, t, ch, 8, lane);
                #pragma unroll
                for (int mt2 = 0; mt2 < 2; ++mt2) {
                    acc[mt2][tt] = MFMA(ah[mt2], bh, acc[mt2][tt]);
                    acc[mt2][tt] = MFMA(ah[mt2], bl_, acc[mt2][tt]);
                    acc[mt2][tt] = MFMA(al[mt2], bh, acc[mt2][tt]);
                }
            }
        }
    }
    __syncthreads();                                // audio dead
    for (int i = tid; i < 16128; i += 512) ((u32*)uni)[i] = 0u;   // zero FULL mag union (hi+lo planes)
    __syncthreads();
    // ---- magnitude epilogue -> mag LDS ----
    #pragma unroll
    for (int tt = 0; tt < 5; ++tt) {
        if (tt < tcnt) {
            int n = (g * 4 + tt) * 16 + m;
            #pragma unroll
            for (int mt2 = 0; mt2 < 2; ++mt2)
                #pragma unroll
                for (int r = 0; r < 4; ++r) {
                    float vv = acc[mt2][tt][r];
                    float s = vv * vv;
                    s += __shfl_xor(s, 1);
                    if (!(n & 1)) {
                        int R = (wh * 2 + mt2) * 16 + quad * 4 + r;
                        int bb = R >> 2, t = R & 3, c = n >> 1;
                        float sv = sqrtf(s);
                        u16 h = f2bf(sv);
                        int phys = (bb * 6 + t + 1) * 168 + c;
                        mAh[phys] = h;
                        mAl[phys] = f2bf(sv - bf2f(h));
                    }
                }
        }
    }
    __syncthreads();
    // ---- GEMM2 (enc1): wave (wh,g): mts {2wh,2wh+1}, nts {2g,2g+1}; K = 3 taps x 5 ch ----
    const u16* B1h = wsu + P_B1;
    const u16* B1l = wsu + P_B1 + S_B1;
    f32x4 acc2[2][2];
    #pragma unroll
    for (int mt2 = 0; mt2 < 2; ++mt2)
        #pragma unroll
        for (int d = 0; d < 2; ++d) acc2[mt2][d] = (f32x4){0.f, 0.f, 0.f, 0.f};
    for (int kk = 0; kk < 3; ++kk) {
        for (int ch = 0; ch < 5; ++ch) {
            bf16x8 ah[2], al[2];
            #pragma unroll
            for (int mt2 = 0; mt2 < 2; ++mt2) {
                int Rm = (wh * 2 + mt2) * 16 + m;
                int phys = ((Rm >> 2) * 6 + (Rm & 3) + kk) * 168 + ch * 32 + quad * 8;
                ah[mt2] = *(const bf16x8*)(mAh + phys);
                al[mt2] = *(const bf16x8*)(mAl + phys);
            }
            #pragma unroll
            for (int d = 0; d < 2; ++d) {
                int nt = 2 * g + d;
                bf16x8 bh = bfrag(B1h + kk * 20480, nt, ch, 5, lane);
                bf16x8 bl_ = bfrag(B1l + kk * 20480, nt, ch, 5, lane);
                #pragma unroll
                for (int mt2 = 0; mt2 < 2; ++mt2) {
                    acc2[mt2][d] = MFMA(ah[mt2], bh, acc2[mt2][d]);
                    acc2[mt2][d] = MFMA(ah[mt2], bl_, acc2[mt2][d]);
                    acc2[mt2][d] = MFMA(al[mt2], bh, acc2[mt2][d]);
                }
            }
        }
    }
    __syncthreads();                                // mag dead
    // ---- e1 -> LDS (split), h -> xh cols 128..255 ----
    #pragma unroll
    for (int d = 0; d < 2; ++d) {
        int n = (2 * g + d) * 16 + m;
        float bv = b1[n];
        #pragma unroll
        for (int mt2 = 0; mt2 < 2; ++mt2)
            #pragma unroll
            for (int r = 0; r < 4; ++r) {
                int R = (wh * 2 + mt2) * 16 + quad * 4 + r;
                float vv = fmaxf(acc2[mt2][d][r] + bv, 0.f);
                u16 h = f2bf(vv);
                int phys = (R >> 2) * 520 + (R & 3) * 128 + n;
                eAh[phys] = h;
                eAl[phys] = f2bf(vv - bf2f(h));
            }
    }
    for (int i = tid; i < 16 * 32; i += 512) {
        int row = i >> 5, c4 = (i & 31) * 4;
        float4 v = *(const float4*)(hin + (size_t)(b0 + row) * 128 + c4);
        split_store4(v, xhh + row * 264 + 128 + c4, xhl + row * 264 + 128 + c4);
    }
    __syncthreads();
    // ---- enc2: waves 0-1 = enc2a (K=256), waves 2-3 = enc2b (K=384); 2 nt each ----
    if (w < 4) {
        const int isB = w >> 1, ntp = w & 1;
        const int awoff = isB ? 128 : 0;
        const int nch = isB ? 12 : 8;
        const u16* Bh = wsu + (isB ? P_B2B : P_B2A);
        const u16* Bl = Bh + (isB ? S_B2B : S_B2A);
        f32x4 a2[2];
        a2[0] = (f32x4){0.f, 0.f, 0.f, 0.f};
        a2[1] = (f32x4){0.f, 0.f, 0.f, 0.f};
        for (int ch = 0; ch < nch; ++ch) {
            int phys = m * 520 + awoff + ch * 32 + quad * 8;
            bf16x8 ah = *(const bf16x8*)(eAh + phys);
            bf16x8 al = *(const bf16x8*)(eAl + phys);
            #pragma unroll
            for (int d = 0; d < 2; ++d) {
                int nt = 2 * ntp + d;
                bf16x8 bh = bfrag(Bh, nt, ch, nch, lane);
                bf16x8 bl_ = bfrag(Bl, nt, ch, nch, lane);
                a2[d] = MFMA(ah, bh, a2[d]);
                a2[d] = MFMA(ah, bl_, a2[d]);
                a2[d] = MFMA(al, bh, a2[d]);
            }
        }
        #pragma unroll
        for (int d = 0; d < 2; ++d) {
            const int oc = (2 * ntp + d) * 16 + m;
            const float bv = b2[oc];
            const int col = isB * 64 + oc;
            #pragma unroll
            for (int r = 0; r < 4; ++r) {
                int row = quad * 4 + r;
                float vv = fmaxf(a2[d][r] + bv, 0.f);
                u16 h = f2bf(vv);
                s2h[row * 136 + col] = h;
                s2l[row * 136 + col] = f2bf(vv - bf2f(h));
            }
        }
    }
    __syncthreads();
    // ---- enc3: waves 0-1, 2 nt each; K=128 (4 ch), N=64 ----
    if (w < 2) {
        const u16* Bh = wsu + P_B3;
        const u16* Bl = Bh + S_B3;
        f32x4 a3[2];
        a3[0] = (f32x4){0.f, 0.f, 0.f, 0.f};
        a3[1] = (f32x4){0.f, 0.f, 0.f, 0.f};
        for (int ch = 0; ch < 4; ++ch) {
            int phys = m * 136 + ch * 32 + quad * 8;
            bf16x8 ah = *(const bf16x8*)(s2h + phys);
            bf16x8 al = *(const bf16x8*)(s2l + phys);
            #pragma unroll
            for (int d = 0; d < 2; ++d) {
                int nt = 2 * w + d;
                bf16x8 bh = bfrag(Bh, nt, ch, 4, lane);
                bf16x8 bl_ = bfrag(Bl, nt, ch, 4, lane);
                a3[d] = MFMA(ah, bh, a3[d]);
                a3[d] = MFMA(ah, bl_, a3[d]);
                a3[d] = MFMA(al, bh, a3[d]);
            }
        }
        #pragma unroll
        for (int d = 0; d < 2; ++d) {
            const int n = (2 * w + d) * 16 + m;
            const float bv = b3[n];
            #pragma unroll
            for (int r = 0; r < 4; ++r) {
                int row = quad * 4 + r;
                float vv = fmaxf(a3[d][r] + bv, 0.f);
                u16 h = f2bf(vv);
                s3h[row * 72 + n] = h;
                s3l[row * 72 + n] = f2bf(vv - bf2f(h));
            }
        }
    }
    __syncthreads();
    // ---- enc4: waves 0-3, 2 nt each; K=64 (2 ch), N=128 -> x into xh cols 0..127 ----
    if (w < 4) {
        const u16* Bh = wsu + P_B4;
        const u16* Bl = Bh + S_B4;
        f32x4 a4[2];
        a4[0] = (f32x4){0.f, 0.f, 0.f, 0.f};
        a4[1] = (f32x4){0.f, 0.f, 0.f, 0.f};
        for (int ch = 0; ch < 2; ++ch) {
            int phys = m * 72 + ch * 32 + quad * 8;
            bf16x8 ah = *(const bf16x8*)(s3h + phys);
            bf16x8 al = *(const bf16x8*)(s3l + phys);
            #pragma unroll
            for (int d = 0; d < 2; ++d) {
                int nt = 2 * w + d;
                bf16x8 bh = bfrag(Bh, nt, ch, 2, lane);
                bf16x8 bl_ = bfrag(Bl, nt, ch, 2, lane);
                a4[d] = MFMA(ah, bh, a4[d]);
                a4[d] = MFMA(ah, bl_, a4[d]);
                a4[d] = MFMA(al, bh, a4[d]);
            }
        }
        #pragma unroll
        for (int d = 0; d < 2; ++d) {
            const int n = (2 * w + d) * 16 + m;
            const float bv = b4[n];
            #pragma unroll
            for (int r = 0; r < 4; ++r) {
                int row = quad * 4 + r;
                float vv = fmaxf(a4[d][r] + bv, 0.f);
                u16 h = f2bf(vv);
                xhh[row * 264 + n] = h;
                xhl[row * 264 + n] = f2bf(vv - bf2f(h));
            }
        }
    }
    __syncthreads();
    // ---- LSTM: waves 0-3; wave owns j-tiles {2w,2w+1} x all 4 gates; K=256 (8 ch) ----
    if (w < 4) {
        const u16* BLh = wsu + P_BL;
        const u16* BLl = BLh + S_BL;
        f32x4 ag[4][2];
        #pragma unroll
        for (int gg = 0; gg < 4; ++gg)
            #pragma unroll
            for (int d = 0; d < 2; ++d) ag[gg][d] = (f32x4){0.f, 0.f, 0.f, 0.f};
        for (int ch = 0; ch < 8; ++ch) {
            int phys = m * 264 + ch * 32 + quad * 8;
            bf16x8 ah = *(const bf16x8*)(xhh + phys);
            bf16x8 al = *(const bf16x8*)(xhl + phys);
            #pragma unroll
            for (int gg = 0; gg < 4; ++gg)
                #pragma unroll
                for (int d = 0; d < 2; ++d) {
                    int nt = gg * 8 + 2 * w + d;
                    bf16x8 bh = bfrag(BLh, nt, ch, 8, lane);
                    bf16x8 bl_ = bfrag(BLl, nt, ch, 8, lane);
                    ag[gg][d] = MFMA(ah, bh, ag[gg][d]);
                    ag[gg][d] = MFMA(ah, bl_, ag[gg][d]);
                    ag[gg][d] = MFMA(al, bh, ag[gg][d]);
                }
        }
        float partial[4] = {0.f, 0.f, 0.f, 0.f};
        #pragma unroll
        for (int d = 0; d < 2; ++d) {
            const int j = (2 * w + d) * 16 + m;
            const float bi = bxi[j] + bhi[j];
            const float bff = bxf[j] + bhf[j];
            const float bgg = bxg[j] + bhg[j];
            const float boo = bxo[j] + bho[j];
            const float cwj = cw[j];
            #pragma unroll
            for (int r = 0; r < 4; ++r) {
                const int b = b0 + quad * 4 + r;
                const float ig = sigm(ag[0][d][r] + bi);
                const float fg = sigm(ag[1][d][r] + bff);
                const float gg = tanhf(ag[2][d][r] + bgg);
                const float og = sigm(ag[3][d][r] + boo);
                const float ci = cin[(size_t)b * 128 + j];
                const float co = fg * ci + ig * gg;
                const float ho = og * tanhf(co);
                out[(size_t)BATCH + (size_t)b * 128 + j] = ho;
                out[(size_t)BATCH + (size_t)BATCH * 128 + (size_t)b * 128 + j] = co;
                partial[r] += fmaxf(ho, 0.f) * cwj;
            }
        }
        #pragma unroll
        for (int off = 1; off < 16; off <<= 1)
            #pragma unroll
            for (int r = 0; r < 4; ++r) partial[r] += __shfl_xor(partial[r], off);
        if (m == 0) {
            #pragma unroll
            for (int r = 0; r < 4; ++r) pr[w * 16 + quad * 4 + r] = partial[r];
        }
    }
    __syncthreads();
    if (tid < 16) {
        float s = cb[0];
        #pragma unroll
        for (int gg = 0; gg < 4; ++gg) s += pr[gg * 16 + tid];
        out[b0 + tid] = sigm(s);
    }
}

extern "C" void kernel_launch(void* const* d_in, const int* in_sizes, int n_in,
                              void* d_out, int out_size, void* d_ws, size_t ws_size,
                              hipStream_t stream) {
    const float* audio = (const float*)d_in[0];
    const float* hin   = (const float*)d_in[1];
    const float* cin   = (const float*)d_in[2];
    const float* fb    = (const float*)d_in[3];
    const float* w1    = (const float*)d_in[4];
    const float* b1    = (const float*)d_in[5];
    const float* w2    = (const float*)d_in[6];
    const float* b2    = (const float*)d_in[7];
    const float* w3    = (const float*)d_in[8];
    const float* b3    = (const float*)d_in[9];
    const float* w4    = (const float*)d_in[10];
    const float* b4    = (const float*)d_in[11];
    const float* wi    = (const float*)d_in[12];
    const float* wf    = (const float*)d_in[13];
    const float* wg    = (const float*)d_in[14];
    const float* wo    = (const float*)d_in[15];
    const float* ui    = (const float*)d_in[16];
    const float* uf    = (const float*)d_in[17];
    const float* ug    = (const float*)d_in[18];
    const float* uo    = (const float*)d_in[19];
    const float* bxi   = (const float*)d_in[20];
    const float* bxf   = (const float*)d_in[21];
    const float* bxg   = (const float*)d_in[22];
    const float* bxo   = (const float*)d_in[23];
    const float* bhi   = (const float*)d_in[24];
    const float* bhf   = (const float*)d_in[25];
    const float* bhg   = (const float*)d_in[26];
    const float* bho   = (const float*)d_in[27];
    const float* cw    = (const float*)d_in[28];
    const float* cb    = (const float*)d_in[29];
    float* out = (float*)d_out;

    u16* wsu = (u16*)d_ws;

    k_prep<<<640, 256, 0, stream>>>(fb, w1, w2, w3, w4, wi, wf, wg, wo, ui, uf, ug, uo, wsu);
    k_all<<<BATCH / 16, 512, 0, stream>>>(audio, wsu, hin, cin, b1, b2, b3, b4,
                                          bxi, bxf, bxg, bxo, bhi, bhf, bhg, bho,
                                          cw, cb, out);
}

// Round 6
// 161.348 us; speedup vs baseline: 1.1707x; 1.1579x over previous
//
#include <hip/hip_runtime.h>
#include <math.h>

#define BATCH 8192
typedef unsigned short u16;
typedef unsigned int u32;
typedef _Float16 f16;
typedef __attribute__((ext_vector_type(8))) _Float16 f16x8;
typedef __attribute__((ext_vector_type(4))) float f32x4;
typedef __attribute__((ext_vector_type(4))) unsigned short u16x4;

__device__ __forceinline__ float sigm(float v) { return 1.0f / (1.0f + __expf(-v)); }
__device__ __forceinline__ u16 f2h(float f) {
    union { f16 h; u16 u; } v; v.h = (f16)f;   // v_cvt_f16_f32, RNE
    return v.u;
}
// fragment-linear B: element [(nt*nch + ch)*64 + lane]*8 + e  ==  B[nt*16+(lane&15)][ch*32+(lane>>4)*8+e]
__device__ __forceinline__ f16x8 ffrag(const u16* Bf, int nt, int ch, int nch, int lane) {
    return *(const f16x8*)(Bf + (((size_t)nt * nch + ch) * 64 + lane) * 8);
}
#define MFMA16(a, b, c) __builtin_amdgcn_mfma_f32_16x16x32_f16(a, b, c, 0, 0, 0)

// ---------------- workspace layout (u16 elements, fp16, SINGLE plane) ----------------
#define S_FBT 69632   // [17 nt][8 ch] frag-linear, n<272, k<256
#define S_B1  61440   // 3 taps x [8 nt][5 ch], n<128, k<160
#define S_B2A 16384   // [4 nt][8 ch]
#define S_B2B 24576   // [4 nt][12 ch]
#define S_B3  8192    // [4 nt][4 ch]
#define S_B4  8192    // [8 nt][2 ch]
#define S_BL  131072  // [32 nt][8 ch]  n = gate*128+j, k: 0..127 W / 128..255 U
#define P_FBT 0
#define P_B1  69632
#define P_B2A 131072
#define P_B2B 147456
#define P_B3  172032
#define P_B4  180224
#define P_BL  188416
#define N_PREP 319488

// ---------------- k_prep: build fragment-linear fp16 B planes ----------------
__global__ __launch_bounds__(256) void k_prep(const float* __restrict__ fb,
                                              const float* __restrict__ w1, const float* __restrict__ w2,
                                              const float* __restrict__ w3, const float* __restrict__ w4,
                                              const float* __restrict__ wi, const float* __restrict__ wf,
                                              const float* __restrict__ wg, const float* __restrict__ wo,
                                              const float* __restrict__ ui, const float* __restrict__ uf,
                                              const float* __restrict__ ug, const float* __restrict__ uo,
                                              u16* __restrict__ wsu) {
    const float* Ws[8] = {wi, wf, wg, wo, ui, uf, ug, uo};
    for (int i = blockIdx.x * 256 + threadIdx.x; i < N_PREP; i += gridDim.x * 256) {
        int r = i;
        float v; int P, idx;
        if (r < S_FBT) {                                    // FBT nch=8
            int f = r >> 9, lane = (r & 511) >> 3, e = r & 7;
            int n = (f >> 3) * 16 + (lane & 15), k = (f & 7) * 32 + (lane >> 4) * 8 + e;
            int c = n >> 1, part = n & 1;
            v = (n < 258) ? fb[(size_t)(c + part * 129) * 256 + k] : 0.f;
            P = P_FBT; idx = r;
        } else if ((r -= S_FBT) < S_B1) {                   // B1: 3 taps, nch=5
            int kk = r / 20480, r2 = r - kk * 20480;
            int f = r2 >> 9, lane = (r2 & 511) >> 3, e = r2 & 7;
            int n = (f / 5) * 16 + (lane & 15), k = (f % 5) * 32 + (lane >> 4) * 8 + e;
            v = (k < 129) ? w1[(size_t)n * 387 + k * 3 + kk] : 0.f;
            P = P_B1; idx = r;
        } else if ((r -= S_B1) < S_B2A) {                   // B2A nch=8
            int f = r >> 9, lane = (r & 511) >> 3, e = r & 7;
            int n = (f >> 3) * 16 + (lane & 15), k = (f & 7) * 32 + (lane >> 4) * 8 + e;
            v = w2[(size_t)n * 384 + (k & 127) * 3 + (k >> 7) + 1];
            P = P_B2A; idx = r;
        } else if ((r -= S_B2A) < S_B2B) {                  // B2B nch=12
            int f = r >> 9, lane = (r & 511) >> 3, e = r & 7;
            int n = (f / 12) * 16 + (lane & 15), k = (f % 12) * 32 + (lane >> 4) * 8 + e;
            v = w2[(size_t)n * 384 + (k & 127) * 3 + (k >> 7)];
            P = P_B2B; idx = r;
        } else if ((r -= S_B2B) < S_B3) {                   // B3 nch=4
            int f = r >> 9, lane = (r & 511) >> 3, e = r & 7;
            int n = (f >> 2) * 16 + (lane & 15), k = (f & 3) * 32 + (lane >> 4) * 8 + e;
            v = w3[(size_t)n * 192 + (k & 63) * 3 + (k >> 6) + 1];
            P = P_B3; idx = r;
        } else if ((r -= S_B3) < S_B4) {                    // B4 nch=2
            int f = r >> 9, lane = (r & 511) >> 3, e = r & 7;
            int n = (f >> 1) * 16 + (lane & 15), k = (f & 1) * 32 + (lane >> 4) * 8 + e;
            v = w4[(size_t)n * 192 + k * 3 + 1];
            P = P_B4; idx = r;
        } else {                                            // BL nch=8
            r -= S_B4;
            int f = r >> 9, lane = (r & 511) >> 3, e = r & 7;
            int n = (f >> 3) * 16 + (lane & 15), k = (f & 7) * 32 + (lane >> 4) * 8 + e;
            int g = n >> 7, j = n & 127;
            v = Ws[g + ((k >= 128) ? 4 : 0)][(size_t)j * 128 + (k & 127)];
            P = P_BL; idx = r;
        }
        wsu[P + idx] = f2h(v);
    }
}

// ---------------- k_all: STFT -> mag -> enc1 -> enc2 -> enc3 -> enc4 -> LSTM -> head ----------------
// Round-0 structure (8 waves every phase, 16 batches, grid 512 = 2 blocks/CU), datapath = fp16:
// activations AND weights fp16 (eps 2^-11, 4x better than bf16), ONE mfma_f32_16x16x32_f16 per
// (A,B) pair (round 0 used 3 bf16 MFMAs for split emulation). MFMA work -67%, B LDS reads halved.
// Error calibration: r5 measured 2.34e-2 @ bf16 A-only quantization (2^-9); fp16 doubles the
// error-source count (weights now inexact) but each is 4x smaller -> predicted ~1.2e-2 < 2e-2.
// LDS union (u16), 16128 elems = 31.5 KB, time-multiplexed:
//   phase A: audio  aA[0,11520)   stride 720 (conflict-free)
//   phase B: mag    mA[0,16128)   rows bb*6+tp, stride 168  (zero FULL plane for pads!)
//   phase C: e1     eA[0,8320)    stride 520
//            s2 [8320,10496) s3 [10496,11648) xh [11648,15872) pr [15872,16128)
__global__ __launch_bounds__(512, 4) void k_all(const float* __restrict__ audio,
                                             const u16* __restrict__ wsu,
                                             const float* __restrict__ hin, const float* __restrict__ cin,
                                             const float* __restrict__ b1, const float* __restrict__ b2,
                                             const float* __restrict__ b3, const float* __restrict__ b4,
                                             const float* __restrict__ bxi, const float* __restrict__ bxf,
                                             const float* __restrict__ bxg, const float* __restrict__ bxo,
                                             const float* __restrict__ bhi, const float* __restrict__ bhf,
                                             const float* __restrict__ bhg, const float* __restrict__ bho,
                                             const float* __restrict__ cw, const float* __restrict__ cb,
                                             float* __restrict__ out) {
    __shared__ __align__(16) u16 uni[16128];
    u16* aA = uni;
    u16* mA = uni;
    u16* eA = uni;
    u16* s2 = uni + 8320;
    u16* s3 = uni + 10496;
    u16* xh = uni + 11648;
    float* pr = (float*)(uni + 15872);
    const int tid = threadIdx.x;
    const int b0 = blockIdx.x << 4;
    // ---- phase A: stage audio (fp16, reflect pad) ----
    for (int i = tid; i < 16 * 160; i += 512) {
        int bb = i / 160, j4 = (i - bb * 160) * 4;
        const float* ap = audio + (size_t)(b0 + bb) * 576;
        float4 v;
        if (j4 < 576) v = *(const float4*)(ap + j4);
        else { v.x = ap[1150 - j4]; v.y = ap[1149 - j4]; v.z = ap[1148 - j4]; v.w = ap[1147 - j4]; }
        int phys = bb * 720 + j4 + (j4 >> 7) * 8;
        u16x4 hv = {f2h(v.x), f2h(v.y), f2h(v.z), f2h(v.w)};
        *(u16x4*)(aA + phys) = hv;
    }
    __syncthreads();
    const int lane = tid & 63, w = tid >> 6;
    const int m = lane & 15, quad = lane >> 4;
    // ---- GEMM1 (STFT): wave w owns nt = 2w..2w+1 (w==7 also nt=16), mt=4 ----
    const u16* fbT = wsu + P_FBT;
    const int tcnt = (w == 7) ? 3 : 2;
    f32x4 acc[4][3];
    #pragma unroll
    for (int mt = 0; mt < 4; ++mt)
        #pragma unroll
        for (int t = 0; t < 3; ++t) acc[mt][t] = (f32x4){0.f, 0.f, 0.f, 0.f};
    for (int ch = 0; ch < 8; ++ch) {
        f16x8 ah[4];
        #pragma unroll
        for (int mt = 0; mt < 4; ++mt) {
            int Rm = mt * 16 + m;
            int phys = (Rm >> 2) * 720 + (Rm & 3) * 136 + ch * 32 + quad * 8 + ((ch >= 4) ? 8 : 0);
            ah[mt] = *(const f16x8*)(aA + phys);
        }
        #pragma unroll
        for (int tt = 0; tt < 3; ++tt) {
            if (tt < tcnt) {
                int t = w * 2 + tt;
                f16x8 bh = ffrag(fbT, t, ch, 8, lane);
                #pragma unroll
                for (int mt = 0; mt < 4; ++mt)
                    acc[mt][tt] = MFMA16(ah[mt], bh, acc[mt][tt]);
            }
        }
    }
    __syncthreads();                                // audio dead
    for (int i = tid; i < 8064; i += 512) ((u32*)uni)[i] = 0u;   // zero FULL mag plane (16128 u16)
    __syncthreads();
    // ---- magnitude epilogue -> mag LDS ----
    #pragma unroll
    for (int tt = 0; tt < 3; ++tt) {
        if (tt < tcnt) {
            int n = (w * 2 + tt) * 16 + m;
            #pragma unroll
            for (int mt = 0; mt < 4; ++mt)
                #pragma unroll
                for (int r = 0; r < 4; ++r) {
                    float vv = acc[mt][tt][r];
                    float s = vv * vv;
                    s += __shfl_xor(s, 1);
                    if (!(n & 1)) {
                        int R = mt * 16 + quad * 4 + r;
                        int bb = R >> 2, t = R & 3, c = n >> 1;
                        mA[(bb * 6 + t + 1) * 168 + c] = f2h(sqrtf(s));
                    }
                }
        }
    }
    __syncthreads();
    // ---- GEMM2 (enc1): wave w owns nt = w (N=128), mt=4, K = 3 taps x 5 ch ----
    const u16* B1p = wsu + P_B1;
    f32x4 acc2[4];
    #pragma unroll
    for (int mt = 0; mt < 4; ++mt) acc2[mt] = (f32x4){0.f, 0.f, 0.f, 0.f};
    for (int kk = 0; kk < 3; ++kk) {
        for (int ch = 0; ch < 5; ++ch) {
            f16x8 bh = ffrag(B1p + kk * 20480, w, ch, 5, lane);
            #pragma unroll
            for (int mt = 0; mt < 4; ++mt) {
                int Rm = mt * 16 + m;
                int phys = ((Rm >> 2) * 6 + (Rm & 3) + kk) * 168 + ch * 32 + quad * 8;
                f16x8 ah = *(const f16x8*)(mA + phys);
                acc2[mt] = MFMA16(ah, bh, acc2[mt]);
            }
        }
    }
    __syncthreads();                                // mag dead
    // ---- e1 -> LDS, h -> xh cols 128..255 ----
    {
        int n = w * 16 + m;
        float bv = b1[n];
        #pragma unroll
        for (int mt = 0; mt < 4; ++mt)
            #pragma unroll
            for (int r = 0; r < 4; ++r) {
                int R = mt * 16 + quad * 4 + r;
                float vv = fmaxf(acc2[mt][r] + bv, 0.f);
                eA[(R >> 2) * 520 + (R & 3) * 128 + n] = f2h(vv);
            }
    }
    for (int i = tid; i < 16 * 32; i += 512) {
        int row = i >> 5, c4 = (i & 31) * 4;
        float4 v = *(const float4*)(hin + (size_t)(b0 + row) * 128 + c4);
        u16x4 hv = {f2h(v.x), f2h(v.y), f2h(v.z), f2h(v.w)};
        *(u16x4*)(xh + row * 264 + 128 + c4) = hv;
    }
    __syncthreads();
    // ---- enc2: waves 0-3 = enc2a (K=256), waves 4-7 = enc2b (K=384) ----
    {
        const int isB = w >> 2, nt = w & 3;
        const int awoff = isB ? 128 : 0;
        const int nch = isB ? 12 : 8;
        const u16* Bp = wsu + (isB ? P_B2B : P_B2A);
        f32x4 a2 = (f32x4){0.f, 0.f, 0.f, 0.f};
        for (int ch = 0; ch < nch; ++ch) {
            int phys = m * 520 + awoff + ch * 32 + quad * 8;
            f16x8 ah = *(const f16x8*)(eA + phys);
            f16x8 bh = ffrag(Bp, nt, ch, nch, lane);
            a2 = MFMA16(ah, bh, a2);
        }
        const int oc = nt * 16 + m;
        const float bv = b2[oc];
        const int col = isB * 64 + oc;
        #pragma unroll
        for (int r = 0; r < 4; ++r) {
            int row = quad * 4 + r;
            float vv = fmaxf(a2[r] + bv, 0.f);
            s2[row * 136 + col] = f2h(vv);
        }
    }
    __syncthreads();
    // ---- enc3: waves 0-3, K=128 (4 ch), N=64 ----
    if (w < 4) {
        const u16* Bp = wsu + P_B3;
        f32x4 a3 = (f32x4){0.f, 0.f, 0.f, 0.f};
        for (int ch = 0; ch < 4; ++ch) {
            int phys = m * 136 + ch * 32 + quad * 8;
            f16x8 ah = *(const f16x8*)(s2 + phys);
            f16x8 bh = ffrag(Bp, w, ch, 4, lane);
            a3 = MFMA16(ah, bh, a3);
        }
        const int n = w * 16 + m;
        const float bv = b3[n];
        #pragma unroll
        for (int r = 0; r < 4; ++r) {
            int row = quad * 4 + r;
            float vv = fmaxf(a3[r] + bv, 0.f);
            s3[row * 72 + n] = f2h(vv);
        }
    }
    __syncthreads();
    // ---- enc4: all 8 waves, K=64 (2 ch), N=128 -> x into xh cols 0..127 ----
    {
        const u16* Bp = wsu + P_B4;
        f32x4 a4 = (f32x4){0.f, 0.f, 0.f, 0.f};
        for (int ch = 0; ch < 2; ++ch) {
            int phys = m * 72 + ch * 32 + quad * 8;
            f16x8 ah = *(const f16x8*)(s3 + phys);
            f16x8 bh = ffrag(Bp, w, ch, 2, lane);
            a4 = MFMA16(ah, bh, a4);
        }
        const int n = w * 16 + m;
        const float bv = b4[n];
        #pragma unroll
        for (int r = 0; r < 4; ++r) {
            int row = quad * 4 + r;
            float vv = fmaxf(a4[r] + bv, 0.f);
            xh[row * 264 + n] = f2h(vv);
        }
    }
    __syncthreads();
    // ---- LSTM: wave w owns j-tile w x all 4 gates; K=256 (8 ch) ----
    {
        const u16* BLp = wsu + P_BL;
        f32x4 ag[4];
        #pragma unroll
        for (int g = 0; g < 4; ++g) ag[g] = (f32x4){0.f, 0.f, 0.f, 0.f};
        #pragma unroll 2
        for (int ch = 0; ch < 8; ++ch) {
            int phys = m * 264 + ch * 32 + quad * 8;
            f16x8 ah = *(const f16x8*)(xh + phys);
            #pragma unroll
            for (int g = 0; g < 4; ++g) {
                int nt = g * 8 + w;
                f16x8 bh = ffrag(BLp, nt, ch, 8, lane);
                ag[g] = MFMA16(ah, bh, ag[g]);
            }
        }
        float partial[4];
        const int j = w * 16 + m;
        const float bi = bxi[j] + bhi[j];
        const float bff = bxf[j] + bhf[j];
        const float bgg = bxg[j] + bhg[j];
        const float boo = bxo[j] + bho[j];
        const float cwj = cw[j];
        #pragma unroll
        for (int r = 0; r < 4; ++r) {
            const int b = b0 + quad * 4 + r;
            const float ig = sigm(ag[0][r] + bi);
            const float fg = sigm(ag[1][r] + bff);
            const float gg = tanhf(ag[2][r] + bgg);
            const float og = sigm(ag[3][r] + boo);
            const float ci = cin[(size_t)b * 128 + j];
            const float co = fg * ci + ig * gg;
            const float ho = og * tanhf(co);
            out[(size_t)BATCH + (size_t)b * 128 + j] = ho;
            out[(size_t)BATCH + (size_t)BATCH * 128 + (size_t)b * 128 + j] = co;
            partial[r] = fmaxf(ho, 0.f) * cwj;
        }
        #pragma unroll
        for (int off = 1; off < 16; off <<= 1)
            #pragma unroll
            for (int r = 0; r < 4; ++r) partial[r] += __shfl_xor(partial[r], off);
        if (m == 0) {
            #pragma unroll
            for (int r = 0; r < 4; ++r) pr[w * 16 + quad * 4 + r] = partial[r];
        }
    }
    __syncthreads();
    if (tid < 16) {
        float s = cb[0];
        #pragma unroll
        for (int g = 0; g < 8; ++g) s += pr[g * 16 + tid];
        out[b0 + tid] = sigm(s);
    }
}

extern "C" void kernel_launch(void* const* d_in, const int* in_sizes, int n_in,
                              void* d_out, int out_size, void* d_ws, size_t ws_size,
                              hipStream_t stream) {
    const float* audio = (const float*)d_in[0];
    const float* hin   = (const float*)d_in[1];
    const float* cin   = (const float*)d_in[2];
    const float* fb    = (const float*)d_in[3];
    const float* w1    = (const float*)d_in[4];
    const float* b1    = (const float*)d_in[5];
    const float* w2    = (const float*)d_in[6];
    const float* b2    = (const float*)d_in[7];
    const float* w3    = (const float*)d_in[8];
    const float* b3    = (const float*)d_in[9];
    const float* w4    = (const float*)d_in[10];
    const float* b4    = (const float*)d_in[11];
    const float* wi    = (const float*)d_in[12];
    const float* wf    = (const float*)d_in[13];
    const float* wg    = (const float*)d_in[14];
    const float* wo    = (const float*)d_in[15];
    const float* ui    = (const float*)d_in[16];
    const float* uf    = (const float*)d_in[17];
    const float* ug    = (const float*)d_in[18];
    const float* uo    = (const float*)d_in[19];
    const float* bxi   = (const float*)d_in[20];
    const float* bxf   = (const float*)d_in[21];
    const float* bxg   = (const float*)d_in[22];
    const float* bxo   = (const float*)d_in[23];
    const float* bhi   = (const float*)d_in[24];
    const float* bhf   = (const float*)d_in[25];
    const float* bhg   = (const float*)d_in[26];
    const float* bho   = (const float*)d_in[27];
    const float* cw    = (const float*)d_in[28];
    const float* cb    = (const float*)d_in[29];
    float* out = (float*)d_out;

    u16* wsu = (u16*)d_ws;

    k_prep<<<640, 256, 0, stream>>>(fb, w1, w2, w3, w4, wi, wf, wg, wo, ui, uf, ug, uo, wsu);
    k_all<<<BATCH / 16, 512, 0, stream>>>(audio, wsu, hin, cin, b1, b2, b3, b4,
                                          bxi, bxf, bxg, bxo, bhi, bhf, bhg, bho,
                                          cw, cb, out);
}

// Round 7
// 158.928 us; speedup vs baseline: 1.1885x; 1.0152x over previous
//
#include <hip/hip_runtime.h>
#include <math.h>

#define BATCH 8192
typedef unsigned short u16;
typedef unsigned int u32;
typedef _Float16 f16;
typedef __attribute__((ext_vector_type(8))) _Float16 f16x8;
typedef __attribute__((ext_vector_type(4))) float f32x4;
typedef __attribute__((ext_vector_type(4))) unsigned short u16x4;

__device__ __forceinline__ float sigm(float v) { return 1.0f / (1.0f + __expf(-v)); }
__device__ __forceinline__ u16 f2h(float f) {
    union { f16 h; u16 u; } v; v.h = (f16)f;   // v_cvt_f16_f32, RNE
    return v.u;
}
// fragment-linear B: element [(nt*nch + ch)*64 + lane]*8 + e  ==  B[nt*16+(lane&15)][ch*32+(lane>>4)*8+e]
__device__ __forceinline__ f16x8 ffrag(const u16* Bf, int nt, int ch, int nch, int lane) {
    return *(const f16x8*)(Bf + (((size_t)nt * nch + ch) * 64 + lane) * 8);
}
#define MFMA16(a, b, c) __builtin_amdgcn_mfma_f32_16x16x32_f16(a, b, c, 0, 0, 0)

// ---------------- workspace layout (u16 elements, fp16, SINGLE plane) ----------------
#define S_FBT 69632   // [17 nt][8 ch] frag-linear, n<272, k<256
#define S_B1  61440   // 3 taps x [8 nt][5 ch], n<128, k<160
#define S_B2A 16384   // [4 nt][8 ch]
#define S_B2B 24576   // [4 nt][12 ch]
#define S_B3  8192    // [4 nt][4 ch]
#define S_B4  8192    // [8 nt][2 ch]
#define S_BL  131072  // [32 nt][8 ch]  n = gate*128+j, k: 0..127 W / 128..255 U
#define P_FBT 0
#define P_B1  69632
#define P_B2A 131072
#define P_B2B 147456
#define P_B3  172032
#define P_B4  180224
#define P_BL  188416
#define N_PREP 319488

// ---------------- k_prep: build fragment-linear fp16 B planes ----------------
__global__ __launch_bounds__(256) void k_prep(const float* __restrict__ fb,
                                              const float* __restrict__ w1, const float* __restrict__ w2,
                                              const float* __restrict__ w3, const float* __restrict__ w4,
                                              const float* __restrict__ wi, const float* __restrict__ wf,
                                              const float* __restrict__ wg, const float* __restrict__ wo,
                                              const float* __restrict__ ui, const float* __restrict__ uf,
                                              const float* __restrict__ ug, const float* __restrict__ uo,
                                              u16* __restrict__ wsu) {
    const float* Ws[8] = {wi, wf, wg, wo, ui, uf, ug, uo};
    for (int i = blockIdx.x * 256 + threadIdx.x; i < N_PREP; i += gridDim.x * 256) {
        int r = i;
        float v; int P, idx;
        if (r < S_FBT) {                                    // FBT nch=8
            int f = r >> 9, lane = (r & 511) >> 3, e = r & 7;
            int n = (f >> 3) * 16 + (lane & 15), k = (f & 7) * 32 + (lane >> 4) * 8 + e;
            int c = n >> 1, part = n & 1;
            v = (n < 258) ? fb[(size_t)(c + part * 129) * 256 + k] : 0.f;
            P = P_FBT; idx = r;
        } else if ((r -= S_FBT) < S_B1) {                   // B1: 3 taps, nch=5
            int kk = r / 20480, r2 = r - kk * 20480;
            int f = r2 >> 9, lane = (r2 & 511) >> 3, e = r2 & 7;
            int n = (f / 5) * 16 + (lane & 15), k = (f % 5) * 32 + (lane >> 4) * 8 + e;
            v = (k < 129) ? w1[(size_t)n * 387 + k * 3 + kk] : 0.f;
            P = P_B1; idx = r;
        } else if ((r -= S_B1) < S_B2A) {                   // B2A nch=8
            int f = r >> 9, lane = (r & 511) >> 3, e = r & 7;
            int n = (f >> 3) * 16 + (lane & 15), k = (f & 7) * 32 + (lane >> 4) * 8 + e;
            v = w2[(size_t)n * 384 + (k & 127) * 3 + (k >> 7) + 1];
            P = P_B2A; idx = r;
        } else if ((r -= S_B2A) < S_B2B) {                  // B2B nch=12
            int f = r >> 9, lane = (r & 511) >> 3, e = r & 7;
            int n = (f / 12) * 16 + (lane & 15), k = (f % 12) * 32 + (lane >> 4) * 8 + e;
            v = w2[(size_t)n * 384 + (k & 127) * 3 + (k >> 7)];
            P = P_B2B; idx = r;
        } else if ((r -= S_B2B) < S_B3) {                   // B3 nch=4
            int f = r >> 9, lane = (r & 511) >> 3, e = r & 7;
            int n = (f >> 2) * 16 + (lane & 15), k = (f & 3) * 32 + (lane >> 4) * 8 + e;
            v = w3[(size_t)n * 192 + (k & 63) * 3 + (k >> 6) + 1];
            P = P_B3; idx = r;
        } else if ((r -= S_B3) < S_B4) {                    // B4 nch=2
            int f = r >> 9, lane = (r & 511) >> 3, e = r & 7;
            int n = (f >> 1) * 16 + (lane & 15), k = (f & 1) * 32 + (lane >> 4) * 8 + e;
            v = w4[(size_t)n * 192 + k * 3 + 1];
            P = P_B4; idx = r;
        } else {                                            // BL nch=8
            r -= S_B4;
            int f = r >> 9, lane = (r & 511) >> 3, e = r & 7;
            int n = (f >> 3) * 16 + (lane & 15), k = (f & 7) * 32 + (lane >> 4) * 8 + e;
            int g = n >> 7, j = n & 127;
            v = Ws[g + ((k >= 128) ? 4 : 0)][(size_t)j * 128 + (k & 127)];
            P = P_BL; idx = r;
        }
        wsu[P + idx] = f2h(v);
    }
}

// ---------------- k_all: STFT -> mag -> enc1 -> enc2 -> enc3 -> enc4 -> LSTM -> head ----------------
// fp16 datapath (r6), now with DE-ALIASED mag plane: 7 barriers instead of 10.
//   - mag pads zeroed during phase A (overlaps audio global-load latency); zero phase gone
//   - h -> xh staged in phase A (xh dedicated region)
//   - GEMM1 MFMA -> mag epilogue: NO barrier (disjoint per-wave mag cells)
//   - enc1 MFMA -> e1 store: NO barrier (eA aliases dead audio; mag reads disjoint)
// LDS map (u16 offsets), total 31872 = 62.2 KB (2 blocks/CU unchanged, grid 512):
//   aA  [0,11520)  audio, stride 720       | eA [0,8320) after GEMM1 (audio dead)
//   mA  [11520,27648) mag, stride 168      | s2 [11520,13696) s3 [13696,14848)
//                                          | pr [14848,15104) after enc1 (mag dead)
//   xh  [27648,31872) dedicated (staged phase A, cols 0..127 filled by enc4)
__global__ __launch_bounds__(512, 4) void k_all(const float* __restrict__ audio,
                                             const u16* __restrict__ wsu,
                                             const float* __restrict__ hin, const float* __restrict__ cin,
                                             const float* __restrict__ b1, const float* __restrict__ b2,
                                             const float* __restrict__ b3, const float* __restrict__ b4,
                                             const float* __restrict__ bxi, const float* __restrict__ bxf,
                                             const float* __restrict__ bxg, const float* __restrict__ bxo,
                                             const float* __restrict__ bhi, const float* __restrict__ bhf,
                                             const float* __restrict__ bhg, const float* __restrict__ bho,
                                             const float* __restrict__ cw, const float* __restrict__ cb,
                                             float* __restrict__ out) {
    __shared__ __align__(16) u16 uni[31872];
    u16* aA = uni;
    u16* eA = uni;
    u16* mA = uni + 11520;
    u16* s2 = uni + 11520;
    u16* s3 = uni + 13696;
    float* pr = (float*)(uni + 14848);
    u16* xh = uni + 27648;
    const int tid = threadIdx.x;
    const int b0 = blockIdx.x << 4;
    // ---- phase A: stage audio + zero mag plane + stage h (all overlap global-load latency) ----
    for (int i = tid; i < 16 * 160; i += 512) {
        int bb = i / 160, j4 = (i - bb * 160) * 4;
        const float* ap = audio + (size_t)(b0 + bb) * 576;
        float4 v;
        if (j4 < 576) v = *(const float4*)(ap + j4);
        else { v.x = ap[1150 - j4]; v.y = ap[1149 - j4]; v.z = ap[1148 - j4]; v.w = ap[1147 - j4]; }
        int phys = bb * 720 + j4 + (j4 >> 7) * 8;
        u16x4 hv = {f2h(v.x), f2h(v.y), f2h(v.z), f2h(v.w)};
        *(u16x4*)(aA + phys) = hv;
    }
    for (int i = tid; i < 8064; i += 512) ((u32*)mA)[i] = 0u;    // zero mag (pads)
    for (int i = tid; i < 16 * 32; i += 512) {
        int row = i >> 5, c4 = (i & 31) * 4;
        float4 v = *(const float4*)(hin + (size_t)(b0 + row) * 128 + c4);
        u16x4 hv = {f2h(v.x), f2h(v.y), f2h(v.z), f2h(v.w)};
        *(u16x4*)(xh + row * 264 + 128 + c4) = hv;
    }
    __syncthreads();                                             // [1]
    const int lane = tid & 63, w = tid >> 6;
    const int m = lane & 15, quad = lane >> 4;
    // ---- GEMM1 (STFT): wave w owns nt = 2w..2w+1 (w==7 also nt=16), mt=4 ----
    const u16* fbT = wsu + P_FBT;
    const int tcnt = (w == 7) ? 3 : 2;
    f32x4 acc[4][3];
    #pragma unroll
    for (int mt = 0; mt < 4; ++mt)
        #pragma unroll
        for (int t = 0; t < 3; ++t) acc[mt][t] = (f32x4){0.f, 0.f, 0.f, 0.f};
    for (int ch = 0; ch < 8; ++ch) {
        f16x8 ah[4];
        #pragma unroll
        for (int mt = 0; mt < 4; ++mt) {
            int Rm = mt * 16 + m;
            int phys = (Rm >> 2) * 720 + (Rm & 3) * 136 + ch * 32 + quad * 8 + ((ch >= 4) ? 8 : 0);
            ah[mt] = *(const f16x8*)(aA + phys);
        }
        #pragma unroll
        for (int tt = 0; tt < 3; ++tt) {
            if (tt < tcnt) {
                int t = w * 2 + tt;
                f16x8 bh = ffrag(fbT, t, ch, 8, lane);
                #pragma unroll
                for (int mt = 0; mt < 4; ++mt)
                    acc[mt][tt] = MFMA16(ah[mt], bh, acc[mt][tt]);
            }
        }
    }
    // ---- magnitude epilogue -> mag LDS (no barrier: disjoint per-wave (row,col) cells) ----
    #pragma unroll
    for (int tt = 0; tt < 3; ++tt) {
        if (tt < tcnt) {
            int n = (w * 2 + tt) * 16 + m;
            #pragma unroll
            for (int mt = 0; mt < 4; ++mt)
                #pragma unroll
                for (int r = 0; r < 4; ++r) {
                    float vv = acc[mt][tt][r];
                    float s = vv * vv;
                    s += __shfl_xor(s, 1);
                    if (!(n & 1)) {
                        int R = mt * 16 + quad * 4 + r;
                        int bb = R >> 2, t = R & 3, c = n >> 1;
                        mA[(bb * 6 + t + 1) * 168 + c] = f2h(sqrtf(s));
                    }
                }
        }
    }
    __syncthreads();                                             // [2]
    // ---- GEMM2 (enc1): wave w owns nt = w (N=128), mt=4, K = 3 taps x 5 ch ----
    const u16* B1p = wsu + P_B1;
    f32x4 acc2[4];
    #pragma unroll
    for (int mt = 0; mt < 4; ++mt) acc2[mt] = (f32x4){0.f, 0.f, 0.f, 0.f};
    for (int kk = 0; kk < 3; ++kk) {
        for (int ch = 0; ch < 5; ++ch) {
            f16x8 bh = ffrag(B1p + kk * 20480, w, ch, 5, lane);
            #pragma unroll
            for (int mt = 0; mt < 4; ++mt) {
                int Rm = mt * 16 + m;
                int phys = ((Rm >> 2) * 6 + (Rm & 3) + kk) * 168 + ch * 32 + quad * 8;
                f16x8 ah = *(const f16x8*)(mA + phys);
                acc2[mt] = MFMA16(ah, bh, acc2[mt]);
            }
        }
    }
    // ---- e1 -> eA (aliases dead audio; disjoint from mA reads; no barrier) ----
    {
        int n = w * 16 + m;
        float bv = b1[n];
        #pragma unroll
        for (int mt = 0; mt < 4; ++mt)
            #pragma unroll
            for (int r = 0; r < 4; ++r) {
                int R = mt * 16 + quad * 4 + r;
                float vv = fmaxf(acc2[mt][r] + bv, 0.f);
                eA[(R >> 2) * 520 + (R & 3) * 128 + n] = f2h(vv);
            }
    }
    __syncthreads();                                             // [3]
    // ---- enc2: waves 0-3 = enc2a (K=256), waves 4-7 = enc2b (K=384); writes s2 (mag dead) ----
    {
        const int isB = w >> 2, nt = w & 3;
        const int awoff = isB ? 128 : 0;
        const int nch = isB ? 12 : 8;
        const u16* Bp = wsu + (isB ? P_B2B : P_B2A);
        f32x4 a2 = (f32x4){0.f, 0.f, 0.f, 0.f};
        for (int ch = 0; ch < nch; ++ch) {
            int phys = m * 520 + awoff + ch * 32 + quad * 8;
            f16x8 ah = *(const f16x8*)(eA + phys);
            f16x8 bh = ffrag(Bp, nt, ch, nch, lane);
            a2 = MFMA16(ah, bh, a2);
        }
        const int oc = nt * 16 + m;
        const float bv = b2[oc];
        const int col = isB * 64 + oc;
        #pragma unroll
        for (int r = 0; r < 4; ++r) {
            int row = quad * 4 + r;
            float vv = fmaxf(a2[r] + bv, 0.f);
            s2[row * 136 + col] = f2h(vv);
        }
    }
    __syncthreads();                                             // [4]
    // ---- enc3: waves 0-3, K=128 (4 ch), N=64 ----
    if (w < 4) {
        const u16* Bp = wsu + P_B3;
        f32x4 a3 = (f32x4){0.f, 0.f, 0.f, 0.f};
        for (int ch = 0; ch < 4; ++ch) {
            int phys = m * 136 + ch * 32 + quad * 8;
            f16x8 ah = *(const f16x8*)(s2 + phys);
            f16x8 bh = ffrag(Bp, w, ch, 4, lane);
            a3 = MFMA16(ah, bh, a3);
        }
        const int n = w * 16 + m;
        const float bv = b3[n];
        #pragma unroll
        for (int r = 0; r < 4; ++r) {
            int row = quad * 4 + r;
            float vv = fmaxf(a3[r] + bv, 0.f);
            s3[row * 72 + n] = f2h(vv);
        }
    }
    __syncthreads();                                             // [5]
    // ---- enc4: all 8 waves, K=64 (2 ch), N=128 -> x into xh cols 0..127 ----
    {
        const u16* Bp = wsu + P_B4;
        f32x4 a4 = (f32x4){0.f, 0.f, 0.f, 0.f};
        for (int ch = 0; ch < 2; ++ch) {
            int phys = m * 72 + ch * 32 + quad * 8;
            f16x8 ah = *(const f16x8*)(s3 + phys);
            f16x8 bh = ffrag(Bp, w, ch, 2, lane);
            a4 = MFMA16(ah, bh, a4);
        }
        const int n = w * 16 + m;
        const float bv = b4[n];
        #pragma unroll
        for (int r = 0; r < 4; ++r) {
            int row = quad * 4 + r;
            float vv = fmaxf(a4[r] + bv, 0.f);
            xh[row * 264 + n] = f2h(vv);
        }
    }
    __syncthreads();                                             // [6]
    // ---- LSTM: wave w owns j-tile w x all 4 gates; K=256 (8 ch) ----
    {
        const u16* BLp = wsu + P_BL;
        f32x4 ag[4];
        #pragma unroll
        for (int g = 0; g < 4; ++g) ag[g] = (f32x4){0.f, 0.f, 0.f, 0.f};
        #pragma unroll 2
        for (int ch = 0; ch < 8; ++ch) {
            int phys = m * 264 + ch * 32 + quad * 8;
            f16x8 ah = *(const f16x8*)(xh + phys);
            #pragma unroll
            for (int g = 0; g < 4; ++g) {
                int nt = g * 8 + w;
                f16x8 bh = ffrag(BLp, nt, ch, 8, lane);
                ag[g] = MFMA16(ah, bh, ag[g]);
            }
        }
        float partial[4];
        const int j = w * 16 + m;
        const float bi = bxi[j] + bhi[j];
        const float bff = bxf[j] + bhf[j];
        const float bgg = bxg[j] + bhg[j];
        const float boo = bxo[j] + bho[j];
        const float cwj = cw[j];
        #pragma unroll
        for (int r = 0; r < 4; ++r) {
            const int b = b0 + quad * 4 + r;
            const float ig = sigm(ag[0][r] + bi);
            const float fg = sigm(ag[1][r] + bff);
            const float gg = tanhf(ag[2][r] + bgg);
            const float og = sigm(ag[3][r] + boo);
            const float ci = cin[(size_t)b * 128 + j];
            const float co = fg * ci + ig * gg;
            const float ho = og * tanhf(co);
            out[(size_t)BATCH + (size_t)b * 128 + j] = ho;
            out[(size_t)BATCH + (size_t)BATCH * 128 + (size_t)b * 128 + j] = co;
            partial[r] = fmaxf(ho, 0.f) * cwj;
        }
        #pragma unroll
        for (int off = 1; off < 16; off <<= 1)
            #pragma unroll
            for (int r = 0; r < 4; ++r) partial[r] += __shfl_xor(partial[r], off);
        if (m == 0) {
            #pragma unroll
            for (int r = 0; r < 4; ++r) pr[w * 16 + quad * 4 + r] = partial[r];
        }
    }
    __syncthreads();                                             // [7]
    if (tid < 16) {
        float s = cb[0];
        #pragma unroll
        for (int g = 0; g < 8; ++g) s += pr[g * 16 + tid];
        out[b0 + tid] = sigm(s);
    }
}

extern "C" void kernel_launch(void* const* d_in, const int* in_sizes, int n_in,
                              void* d_out, int out_size, void* d_ws, size_t ws_size,
                              hipStream_t stream) {
    const float* audio = (const float*)d_in[0];
    const float* hin   = (const float*)d_in[1];
    const float* cin   = (const float*)d_in[2];
    const float* fb    = (const float*)d_in[3];
    const float* w1    = (const float*)d_in[4];
    const float* b1    = (const float*)d_in[5];
    const float* w2    = (const float*)d_in[6];
    const float* b2    = (const float*)d_in[7];
    const float* w3    = (const float*)d_in[8];
    const float* b3    = (const float*)d_in[9];
    const float* w4    = (const float*)d_in[10];
    const float* b4    = (const float*)d_in[11];
    const float* wi    = (const float*)d_in[12];
    const float* wf    = (const float*)d_in[13];
    const float* wg    = (const float*)d_in[14];
    const float* wo    = (const float*)d_in[15];
    const float* ui    = (const float*)d_in[16];
    const float* uf    = (const float*)d_in[17];
    const float* ug    = (const float*)d_in[18];
    const float* uo    = (const float*)d_in[19];
    const float* bxi   = (const float*)d_in[20];
    const float* bxf   = (const float*)d_in[21];
    const float* bxg   = (const float*)d_in[22];
    const float* bxo   = (const float*)d_in[23];
    const float* bhi   = (const float*)d_in[24];
    const float* bhf   = (const float*)d_in[25];
    const float* bhg   = (const float*)d_in[26];
    const float* bho   = (const float*)d_in[27];
    const float* cw    = (const float*)d_in[28];
    const float* cb    = (const float*)d_in[29];
    float* out = (float*)d_out;

    u16* wsu = (u16*)d_ws;

    k_prep<<<640, 256, 0, stream>>>(fb, w1, w2, w3, w4, wi, wf, wg, wo, ui, uf, ug, uo, wsu);
    k_all<<<BATCH / 16, 512, 0, stream>>>(audio, wsu, hin, cin, b1, b2, b3, b4,
                                          bxi, bxf, bxg, bxo, bhi, bhf, bhg, bho,
                                          cw, cb, out);
}

// Round 8
// 155.654 us; speedup vs baseline: 1.2135x; 1.0210x over previous
//
#include <hip/hip_runtime.h>
#include <math.h>

#define BATCH 8192
typedef unsigned short u16;
typedef unsigned int u32;
typedef _Float16 f16;
typedef __attribute__((ext_vector_type(8))) _Float16 f16x8;
typedef __attribute__((ext_vector_type(4))) float f32x4;
typedef __attribute__((ext_vector_type(4))) unsigned short u16x4;

__device__ __forceinline__ float sigm(float v) { return 1.0f / (1.0f + __expf(-v)); }
__device__ __forceinline__ u16 f2h(float f) {
    union { f16 h; u16 u; } v; v.h = (f16)f;   // v_cvt_f16_f32, RNE
    return v.u;
}
// fragment-linear B: element [(nt*nch + ch)*64 + lane]*8 + e  ==  B[nt*16+(lane&15)][ch*32+(lane>>4)*8+e]
__device__ __forceinline__ f16x8 ffrag(const u16* Bf, int nt, int ch, int nch, int lane) {
    return *(const f16x8*)(Bf + (((size_t)nt * nch + ch) * 64 + lane) * 8);
}
#define MFMA16(a, b, c) __builtin_amdgcn_mfma_f32_16x16x32_f16(a, b, c, 0, 0, 0)

// ---------------- workspace layout (u16 elements, fp16, SINGLE plane) ----------------
#define S_FBT 69632   // [17 nt][8 ch] frag-linear, n<272, k<256
#define S_B1  61440   // 3 taps x [8 nt][5 ch], n<128, k<160
#define S_B2A 16384   // [4 nt][8 ch]
#define S_B2B 24576   // [4 nt][12 ch]
#define S_B3  8192    // [4 nt][4 ch]
#define S_B4  8192    // [8 nt][2 ch]
#define S_BL  131072  // [32 nt][8 ch]  n = gate*128+j, k: 0..127 W / 128..255 U
#define P_FBT 0
#define P_B1  69632
#define P_B2A 131072
#define P_B2B 147456
#define P_B3  172032
#define P_B4  180224
#define P_BL  188416
#define N_PREP 319488

// ---------------- k_prep: build fragment-linear fp16 B planes ----------------
__global__ __launch_bounds__(256) void k_prep(const float* __restrict__ fb,
                                              const float* __restrict__ w1, const float* __restrict__ w2,
                                              const float* __restrict__ w3, const float* __restrict__ w4,
                                              const float* __restrict__ wi, const float* __restrict__ wf,
                                              const float* __restrict__ wg, const float* __restrict__ wo,
                                              const float* __restrict__ ui, const float* __restrict__ uf,
                                              const float* __restrict__ ug, const float* __restrict__ uo,
                                              u16* __restrict__ wsu) {
    const float* Ws[8] = {wi, wf, wg, wo, ui, uf, ug, uo};
    for (int i = blockIdx.x * 256 + threadIdx.x; i < N_PREP; i += gridDim.x * 256) {
        int r = i;
        float v; int P, idx;
        if (r < S_FBT) {                                    // FBT nch=8
            int f = r >> 9, lane = (r & 511) >> 3, e = r & 7;
            int n = (f >> 3) * 16 + (lane & 15), k = (f & 7) * 32 + (lane >> 4) * 8 + e;
            int c = n >> 1, part = n & 1;
            v = (n < 258) ? fb[(size_t)(c + part * 129) * 256 + k] : 0.f;
            P = P_FBT; idx = r;
        } else if ((r -= S_FBT) < S_B1) {                   // B1: 3 taps, nch=5
            int kk = r / 20480, r2 = r - kk * 20480;
            int f = r2 >> 9, lane = (r2 & 511) >> 3, e = r2 & 7;
            int n = (f / 5) * 16 + (lane & 15), k = (f % 5) * 32 + (lane >> 4) * 8 + e;
            v = (k < 129) ? w1[(size_t)n * 387 + k * 3 + kk] : 0.f;
            P = P_B1; idx = r;
        } else if ((r -= S_B1) < S_B2A) {                   // B2A nch=8
            int f = r >> 9, lane = (r & 511) >> 3, e = r & 7;
            int n = (f >> 3) * 16 + (lane & 15), k = (f & 7) * 32 + (lane >> 4) * 8 + e;
            v = w2[(size_t)n * 384 + (k & 127) * 3 + (k >> 7) + 1];
            P = P_B2A; idx = r;
        } else if ((r -= S_B2A) < S_B2B) {                  // B2B nch=12
            int f = r >> 9, lane = (r & 511) >> 3, e = r & 7;
            int n = (f / 12) * 16 + (lane & 15), k = (f % 12) * 32 + (lane >> 4) * 8 + e;
            v = w2[(size_t)n * 384 + (k & 127) * 3 + (k >> 7)];
            P = P_B2B; idx = r;
        } else if ((r -= S_B2B) < S_B3) {                   // B3 nch=4
            int f = r >> 9, lane = (r & 511) >> 3, e = r & 7;
            int n = (f >> 2) * 16 + (lane & 15), k = (f & 3) * 32 + (lane >> 4) * 8 + e;
            v = w3[(size_t)n * 192 + (k & 63) * 3 + (k >> 6) + 1];
            P = P_B3; idx = r;
        } else if ((r -= S_B3) < S_B4) {                    // B4 nch=2
            int f = r >> 9, lane = (r & 511) >> 3, e = r & 7;
            int n = (f >> 1) * 16 + (lane & 15), k = (f & 1) * 32 + (lane >> 4) * 8 + e;
            v = w4[(size_t)n * 192 + k * 3 + 1];
            P = P_B4; idx = r;
        } else {                                            // BL nch=8
            r -= S_B4;
            int f = r >> 9, lane = (r & 511) >> 3, e = r & 7;
            int n = (f >> 3) * 16 + (lane & 15), k = (f & 7) * 32 + (lane >> 4) * 8 + e;
            int g = n >> 7, j = n & 127;
            v = Ws[g + ((k >= 128) ? 4 : 0)][(size_t)j * 128 + (k & 127)];
            P = P_BL; idx = r;
        }
        wsu[P + idx] = f2h(v);
    }
}

// ---------------- k_all ----------------
// r7 structure (7 barriers, de-aliased mag, fp16 single-MFMA) + round-8 latency fixes:
//   (a) K-split dual accumulators in enc2/enc3/enc4/LSTM -> 2x independent MFMA chains/wave
//   (b) next-phase B fragments prefetched into registers BEFORE each barrier (compiler
//       cannot hoist global loads across __syncthreads; explicit prefetch removes the
//       ~200-300cyc L2 latency from every post-barrier critical path)
// LDS map unchanged from r7 (62.2 KB, 2 blocks/CU).
__global__ __launch_bounds__(512, 4) void k_all(const float* __restrict__ audio,
                                             const u16* __restrict__ wsu,
                                             const float* __restrict__ hin, const float* __restrict__ cin,
                                             const float* __restrict__ b1, const float* __restrict__ b2,
                                             const float* __restrict__ b3, const float* __restrict__ b4,
                                             const float* __restrict__ bxi, const float* __restrict__ bxf,
                                             const float* __restrict__ bxg, const float* __restrict__ bxo,
                                             const float* __restrict__ bhi, const float* __restrict__ bhf,
                                             const float* __restrict__ bhg, const float* __restrict__ bho,
                                             const float* __restrict__ cw, const float* __restrict__ cb,
                                             float* __restrict__ out) {
    __shared__ __align__(16) u16 uni[31872];
    u16* aA = uni;
    u16* eA = uni;
    u16* mA = uni + 11520;
    u16* s2 = uni + 11520;
    u16* s3 = uni + 13696;
    float* pr = (float*)(uni + 14848);
    u16* xh = uni + 27648;
    const int tid = threadIdx.x;
    const int b0 = blockIdx.x << 4;
    // ---- phase A: stage audio + zero mag plane + stage h ----
    for (int i = tid; i < 16 * 160; i += 512) {
        int bb = i / 160, j4 = (i - bb * 160) * 4;
        const float* ap = audio + (size_t)(b0 + bb) * 576;
        float4 v;
        if (j4 < 576) v = *(const float4*)(ap + j4);
        else { v.x = ap[1150 - j4]; v.y = ap[1149 - j4]; v.z = ap[1148 - j4]; v.w = ap[1147 - j4]; }
        int phys = bb * 720 + j4 + (j4 >> 7) * 8;
        u16x4 hv = {f2h(v.x), f2h(v.y), f2h(v.z), f2h(v.w)};
        *(u16x4*)(aA + phys) = hv;
    }
    for (int i = tid; i < 8064; i += 512) ((u32*)mA)[i] = 0u;    // zero mag (pads)
    for (int i = tid; i < 16 * 32; i += 512) {
        int row = i >> 5, c4 = (i & 31) * 4;
        float4 v = *(const float4*)(hin + (size_t)(b0 + row) * 128 + c4);
        u16x4 hv = {f2h(v.x), f2h(v.y), f2h(v.z), f2h(v.w)};
        *(u16x4*)(xh + row * 264 + 128 + c4) = hv;
    }
    __syncthreads();                                             // [1]
    const int lane = tid & 63, w = tid >> 6;
    const int m = lane & 15, quad = lane >> 4;
    // ---- GEMM1 (STFT): wave w owns nt = 2w..2w+1 (w==7 also nt=16), mt=4 ----
    const u16* fbT = wsu + P_FBT;
    const int tcnt = (w == 7) ? 3 : 2;
    f32x4 acc[4][3];
    #pragma unroll
    for (int mt = 0; mt < 4; ++mt)
        #pragma unroll
        for (int t = 0; t < 3; ++t) acc[mt][t] = (f32x4){0.f, 0.f, 0.f, 0.f};
    for (int ch = 0; ch < 8; ++ch) {
        f16x8 ah[4];
        #pragma unroll
        for (int mt = 0; mt < 4; ++mt) {
            int Rm = mt * 16 + m;
            int phys = (Rm >> 2) * 720 + (Rm & 3) * 136 + ch * 32 + quad * 8 + ((ch >= 4) ? 8 : 0);
            ah[mt] = *(const f16x8*)(aA + phys);
        }
        #pragma unroll
        for (int tt = 0; tt < 3; ++tt) {
            if (tt < tcnt) {
                int t = w * 2 + tt;
                f16x8 bh = ffrag(fbT, t, ch, 8, lane);
                #pragma unroll
                for (int mt = 0; mt < 4; ++mt)
                    acc[mt][tt] = MFMA16(ah[mt], bh, acc[mt][tt]);
            }
        }
    }
    // ---- magnitude epilogue -> mag LDS (no barrier: disjoint per-wave cells) ----
    #pragma unroll
    for (int tt = 0; tt < 3; ++tt) {
        if (tt < tcnt) {
            int n = (w * 2 + tt) * 16 + m;
            #pragma unroll
            for (int mt = 0; mt < 4; ++mt)
                #pragma unroll
                for (int r = 0; r < 4; ++r) {
                    float vv = acc[mt][tt][r];
                    float s = vv * vv;
                    s += __shfl_xor(s, 1);
                    if (!(n & 1)) {
                        int R = mt * 16 + quad * 4 + r;
                        int bb = R >> 2, t = R & 3, c = n >> 1;
                        mA[(bb * 6 + t + 1) * 168 + c] = f2h(sqrtf(s));
                    }
                }
        }
    }
    // ---- prefetch enc1 B (15 frags) before barrier; drain completes them ----
    const u16* B1p = wsu + P_B1;
    f16x8 pB1[15];
    #pragma unroll
    for (int kk = 0; kk < 3; ++kk)
        #pragma unroll
        for (int ch = 0; ch < 5; ++ch)
            pB1[kk * 5 + ch] = ffrag(B1p + kk * 20480, w, ch, 5, lane);
    __syncthreads();                                             // [2]
    // ---- GEMM2 (enc1): wave w owns nt = w (N=128), mt=4, K = 3 taps x 5 ch ----
    f32x4 acc2[4];
    #pragma unroll
    for (int mt = 0; mt < 4; ++mt) acc2[mt] = (f32x4){0.f, 0.f, 0.f, 0.f};
    #pragma unroll
    for (int kk = 0; kk < 3; ++kk) {
        #pragma unroll
        for (int ch = 0; ch < 5; ++ch) {
            f16x8 bh = pB1[kk * 5 + ch];
            #pragma unroll
            for (int mt = 0; mt < 4; ++mt) {
                int Rm = mt * 16 + m;
                int phys = ((Rm >> 2) * 6 + (Rm & 3) + kk) * 168 + ch * 32 + quad * 8;
                f16x8 ah = *(const f16x8*)(mA + phys);
                acc2[mt] = MFMA16(ah, bh, acc2[mt]);
            }
        }
    }
    // ---- e1 -> eA (aliases dead audio; no barrier) ----
    {
        int n = w * 16 + m;
        float bv = b1[n];
        #pragma unroll
        for (int mt = 0; mt < 4; ++mt)
            #pragma unroll
            for (int r = 0; r < 4; ++r) {
                int R = mt * 16 + quad * 4 + r;
                float vv = fmaxf(acc2[mt][r] + bv, 0.f);
                eA[(R >> 2) * 520 + (R & 3) * 128 + n] = f2h(vv);
            }
    }
    // ---- prefetch enc2 B before barrier ----
    const int isB = w >> 2, nt2 = w & 3;
    const int nch2 = isB ? 12 : 8;
    const u16* Bp2 = wsu + (isB ? P_B2B : P_B2A);
    f16x8 pB2[12];
    #pragma unroll
    for (int ch = 0; ch < 8; ++ch) pB2[ch] = ffrag(Bp2, nt2, ch, nch2, lane);
    if (isB) {
        #pragma unroll
        for (int ch = 8; ch < 12; ++ch) pB2[ch] = ffrag(Bp2, nt2, ch, 12, lane);
    }
    __syncthreads();                                             // [3]
    // ---- enc2: waves 0-3 = enc2a (K=256), waves 4-7 = enc2b (K=384); K-split 2 accs ----
    {
        const int awoff = isB ? 128 : 0;
        f32x4 a2a = (f32x4){0.f, 0.f, 0.f, 0.f};
        f32x4 a2b = (f32x4){0.f, 0.f, 0.f, 0.f};
        #pragma unroll
        for (int ch = 0; ch < 8; ++ch) {
            int phys = m * 520 + awoff + ch * 32 + quad * 8;
            f16x8 ah = *(const f16x8*)(eA + phys);
            if (ch & 1) a2b = MFMA16(ah, pB2[ch], a2b);
            else        a2a = MFMA16(ah, pB2[ch], a2a);
        }
        if (isB) {
            #pragma unroll
            for (int ch = 8; ch < 12; ++ch) {
                int phys = m * 520 + awoff + ch * 32 + quad * 8;
                f16x8 ah = *(const f16x8*)(eA + phys);
                if (ch & 1) a2b = MFMA16(ah, pB2[ch], a2b);
                else        a2a = MFMA16(ah, pB2[ch], a2a);
            }
        }
        const int oc = nt2 * 16 + m;
        const float bv = b2[oc];
        const int col = isB * 64 + oc;
        #pragma unroll
        for (int r = 0; r < 4; ++r) {
            int row = quad * 4 + r;
            float vv = fmaxf(a2a[r] + a2b[r] + bv, 0.f);
            s2[row * 136 + col] = f2h(vv);
        }
    }
    // ---- prefetch enc3 B before barrier (waves 0-3) ----
    f16x8 pB3[4];
    if (w < 4) {
        #pragma unroll
        for (int ch = 0; ch < 4; ++ch) pB3[ch] = ffrag(wsu + P_B3, w, ch, 4, lane);
    }
    __syncthreads();                                             // [4]
    // ---- enc3: waves 0-3, K=128 (4 ch), N=64; K-split 2 accs ----
    if (w < 4) {
        f32x4 a3a = (f32x4){0.f, 0.f, 0.f, 0.f};
        f32x4 a3b = (f32x4){0.f, 0.f, 0.f, 0.f};
        #pragma unroll
        for (int ch = 0; ch < 4; ++ch) {
            int phys = m * 136 + ch * 32 + quad * 8;
            f16x8 ah = *(const f16x8*)(s2 + phys);
            if (ch & 1) a3b = MFMA16(ah, pB3[ch], a3b);
            else        a3a = MFMA16(ah, pB3[ch], a3a);
        }
        const int n = w * 16 + m;
        const float bv = b3[n];
        #pragma unroll
        for (int r = 0; r < 4; ++r) {
            int row = quad * 4 + r;
            float vv = fmaxf(a3a[r] + a3b[r] + bv, 0.f);
            s3[row * 72 + n] = f2h(vv);
        }
    }
    // ---- prefetch enc4 B before barrier (all waves) ----
    f16x8 pB4[2];
    #pragma unroll
    for (int ch = 0; ch < 2; ++ch) pB4[ch] = ffrag(wsu + P_B4, w, ch, 2, lane);
    __syncthreads();                                             // [5]
    // ---- enc4: all 8 waves, K=64 (2 ch), N=128; 2 accs ----
    {
        f32x4 a4a = (f32x4){0.f, 0.f, 0.f, 0.f};
        f32x4 a4b = (f32x4){0.f, 0.f, 0.f, 0.f};
        {
            int phys = m * 72 + 0 * 32 + quad * 8;
            a4a = MFMA16(*(const f16x8*)(s3 + phys), pB4[0], a4a);
            phys = m * 72 + 1 * 32 + quad * 8;
            a4b = MFMA16(*(const f16x8*)(s3 + phys), pB4[1], a4b);
        }
        const int n = w * 16 + m;
        const float bv = b4[n];
        #pragma unroll
        for (int r = 0; r < 4; ++r) {
            int row = quad * 4 + r;
            float vv = fmaxf(a4a[r] + a4b[r] + bv, 0.f);
            xh[row * 264 + n] = f2h(vv);
        }
    }
    // ---- prefetch LSTM B for ch 0-1 (8 frags) before barrier ----
    const u16* BLp = wsu + P_BL;
    f16x8 pBL[8];
    #pragma unroll
    for (int ch = 0; ch < 2; ++ch)
        #pragma unroll
        for (int g = 0; g < 4; ++g)
            pBL[g * 2 + ch] = ffrag(BLp, g * 8 + w, ch, 8, lane);
    __syncthreads();                                             // [6]
    // ---- LSTM: wave w owns j-tile w x 4 gates; K=256 (8 ch); K-split 8 accs ----
    {
        f32x4 agA[4], agB[4];
        #pragma unroll
        for (int g = 0; g < 4; ++g) {
            agA[g] = (f32x4){0.f, 0.f, 0.f, 0.f};
            agB[g] = (f32x4){0.f, 0.f, 0.f, 0.f};
        }
        #pragma unroll
        for (int ch = 0; ch < 8; ++ch) {
            int phys = m * 264 + ch * 32 + quad * 8;
            f16x8 ah = *(const f16x8*)(xh + phys);
            #pragma unroll
            for (int g = 0; g < 4; ++g) {
                f16x8 bh = (ch < 2) ? pBL[g * 2 + ch] : ffrag(BLp, g * 8 + w, ch, 8, lane);
                if (ch & 1) agB[g] = MFMA16(ah, bh, agB[g]);
                else        agA[g] = MFMA16(ah, bh, agA[g]);
            }
        }
        float partial[4];
        const int j = w * 16 + m;
        const float bi = bxi[j] + bhi[j];
        const float bff = bxf[j] + bhf[j];
        const float bgg = bxg[j] + bhg[j];
        const float boo = bxo[j] + bho[j];
        const float cwj = cw[j];
        #pragma unroll
        for (int r = 0; r < 4; ++r) {
            const int b = b0 + quad * 4 + r;
            const float ig = sigm(agA[0][r] + agB[0][r] + bi);
            const float fg = sigm(agA[1][r] + agB[1][r] + bff);
            const float gg = tanhf(agA[2][r] + agB[2][r] + bgg);
            const float og = sigm(agA[3][r] + agB[3][r] + boo);
            const float ci = cin[(size_t)b * 128 + j];
            const float co = fg * ci + ig * gg;
            const float ho = og * tanhf(co);
            out[(size_t)BATCH + (size_t)b * 128 + j] = ho;
            out[(size_t)BATCH + (size_t)BATCH * 128 + (size_t)b * 128 + j] = co;
            partial[r] = fmaxf(ho, 0.f) * cwj;
        }
        #pragma unroll
        for (int off = 1; off < 16; off <<= 1)
            #pragma unroll
            for (int r = 0; r < 4; ++r) partial[r] += __shfl_xor(partial[r], off);
        if (m == 0) {
            #pragma unroll
            for (int r = 0; r < 4; ++r) pr[w * 16 + quad * 4 + r] = partial[r];
        }
    }
    __syncthreads();                                             // [7]
    if (tid < 16) {
        float s = cb[0];
        #pragma unroll
        for (int g = 0; g < 8; ++g) s += pr[g * 16 + tid];
        out[b0 + tid] = sigm(s);
    }
}

extern "C" void kernel_launch(void* const* d_in, const int* in_sizes, int n_in,
                              void* d_out, int out_size, void* d_ws, size_t ws_size,
                              hipStream_t stream) {
    const float* audio = (const float*)d_in[0];
    const float* hin   = (const float*)d_in[1];
    const float* cin   = (const float*)d_in[2];
    const float* fb    = (const float*)d_in[3];
    const float* w1    = (const float*)d_in[4];
    const float* b1    = (const float*)d_in[5];
    const float* w2    = (const float*)d_in[6];
    const float* b2    = (const float*)d_in[7];
    const float* w3    = (const float*)d_in[8];
    const float* b3    = (const float*)d_in[9];
    const float* w4    = (const float*)d_in[10];
    const float* b4    = (const float*)d_in[11];
    const float* wi    = (const float*)d_in[12];
    const float* wf    = (const float*)d_in[13];
    const float* wg    = (const float*)d_in[14];
    const float* wo    = (const float*)d_in[15];
    const float* ui    = (const float*)d_in[16];
    const float* uf    = (const float*)d_in[17];
    const float* ug    = (const float*)d_in[18];
    const float* uo    = (const float*)d_in[19];
    const float* bxi   = (const float*)d_in[20];
    const float* bxf   = (const float*)d_in[21];
    const float* bxg   = (const float*)d_in[22];
    const float* bxo   = (const float*)d_in[23];
    const float* bhi   = (const float*)d_in[24];
    const float* bhf   = (const float*)d_in[25];
    const float* bhg   = (const float*)d_in[26];
    const float* bho   = (const float*)d_in[27];
    const float* cw    = (const float*)d_in[28];
    const float* cb    = (const float*)d_in[29];
    float* out = (float*)d_out;

    u16* wsu = (u16*)d_ws;

    k_prep<<<640, 256, 0, stream>>>(fb, w1, w2, w3, w4, wi, wf, wg, wo, ui, uf, ug, uo, wsu);
    k_all<<<BATCH / 16, 512, 0, stream>>>(audio, wsu, hin, cin, b1, b2, b3, b4,
                                          bxi, bxf, bxg, bxo, bhi, bhf, bhg, bho,
                                          cw, cb, out);
}